// Round 1
// baseline (508.930 us; speedup 1.0000x reference)
//
#include <hip/hip_runtime.h>
#include <hip/hip_bf16.h>
#include <math.h>

typedef __attribute__((ext_vector_type(4))) float   f32x4;
typedef __attribute__((ext_vector_type(4))) __bf16  bf16x4;
typedef __attribute__((ext_vector_type(8))) __bf16  bf16x8;
typedef __attribute__((ext_vector_type(8))) unsigned short ushort8;
typedef unsigned short u16;

#define LOG2E 1.44269504088896f

__device__ __forceinline__ u16 f2b(float f) {
    unsigned u = __builtin_bit_cast(unsigned, f);
    u += 0x7fff + ((u >> 16) & 1);          // RNE
    return (u16)(u >> 16);
}
__device__ __forceinline__ float b2f(u16 h) {
    unsigned u = ((unsigned)h) << 16;
    return __builtin_bit_cast(float, u);
}
// async global->LDS, 16B per lane; LDS dest = wave-uniform base + lane*16
__device__ __forceinline__ void gl16(const void* g, void* l) {
    __builtin_amdgcn_global_load_lds((const __attribute__((address_space(1))) void*)g,
                                     (__attribute__((address_space(3))) void*)l, 16, 0, 0);
}
// Load one MFMA operand fragment (16x16x32 bf16): two 16-K halves,
// regs 0-3 <-> k = 4*lg + j ; regs 4-7 <-> k = 16 + 4*lg + j
__device__ __forceinline__ bf16x8 ldfrag(const u16* rowp, int lg) {
    const int ko = lg * 4;
    bf16x4 lo = *(const bf16x4*)(rowp + ko);
    bf16x4 hi = *(const bf16x4*)(rowp + 16 + ko);
    return __builtin_shufflevector(lo, hi, 0, 1, 2, 3, 4, 5, 6, 7);
}

// ---------------- f32 -> bf16 convert ----------------
__global__ void cvt_kernel(const float* __restrict__ src, u16* __restrict__ dst, int n4) {
    int i = blockIdx.x * 256 + threadIdx.x;
    if (i < n4) {
        float4 v = ((const float4*)src)[i];
        ushort4 o = make_ushort4(f2b(v.x), f2b(v.y), f2b(v.z), f2b(v.w));
        ((ushort4*)dst)[i] = o;
    }
}

// ---------------- GEMM: C[M,N] = A[M,K] * Bw[N,K]^T (bf16 in, f32 acc) ----------------
// 128x128 tile, BK=32, 4 waves in 2x2, each wave 64x64 (4x4 fragments)
__global__ __launch_bounds__(256) void gemm_bt(
    const u16* __restrict__ A, const u16* __restrict__ Bw,
    float* __restrict__ Cf, u16* __restrict__ Cb, int M, int N, int K)
{
    __shared__ u16 lsA[128 * 32];
    __shared__ u16 lsB[128 * 32];
    const int tid = threadIdx.x;
    const int lane = tid & 63, wv = tid >> 6;
    const int l15 = lane & 15, lg = lane >> 4;
    const int mblk = blockIdx.y * 128, nblk = blockIdx.x * 128;
    const int m0 = (wv >> 1) * 64, n0 = (wv & 1) * 64;

    f32x4 acc[4][4];
    for (int a = 0; a < 4; ++a)
        for (int b = 0; b < 4; ++b)
            for (int r = 0; r < 4; ++r) acc[a][b][r] = 0.f;

    for (int kt = 0; kt < K; kt += 32) {
#pragma unroll
        for (int r = 0; r < 2; ++r) {
            int c = r * 256 + tid;           // 8-elem chunk id
            int row = c >> 2, col = (c & 3) << 3;
            gl16(A  + (size_t)(mblk + row) * K + kt + col, &lsA[(r * 256 + wv * 64) * 8]);
            gl16(Bw + (size_t)(nblk + row) * K + kt + col, &lsB[(r * 256 + wv * 64) * 8]);
        }
        __syncthreads();
        bf16x8 af[4], bfr[4];
#pragma unroll
        for (int mm = 0; mm < 4; ++mm) af[mm] = ldfrag(&lsA[(m0 + mm * 16 + l15) * 32], lg);
#pragma unroll
        for (int nn = 0; nn < 4; ++nn) bfr[nn] = ldfrag(&lsB[(n0 + nn * 16 + l15) * 32], lg);
#pragma unroll
        for (int mm = 0; mm < 4; ++mm)
#pragma unroll
            for (int nn = 0; nn < 4; ++nn)
                acc[mm][nn] = __builtin_amdgcn_mfma_f32_16x16x32_bf16(af[mm], bfr[nn], acc[mm][nn], 0, 0, 0);
        __syncthreads();
    }
    // C/D layout: col = lane&15, row = (lane>>4)*4 + reg   [m89-verified]
#pragma unroll
    for (int mm = 0; mm < 4; ++mm)
#pragma unroll
        for (int nn = 0; nn < 4; ++nn)
#pragma unroll
            for (int r = 0; r < 4; ++r) {
                int row = mblk + m0 + mm * 16 + lg * 4 + r;
                int col = nblk + n0 + nn * 16 + l15;
                float v = acc[mm][nn][r];
                if (Cf) Cf[(size_t)row * N + col] = v;
                else    Cb[(size_t)row * N + col] = f2b(v);
            }
}

// ---------------- RoPE + relayout (b,s,e) -> (b,h,s,d) ----------------
__global__ void rope_kernel(const u16* __restrict__ Yq, const u16* __restrict__ Yk,
                            const u16* __restrict__ Yv, const int* __restrict__ pos,
                            u16* __restrict__ Qh, u16* __restrict__ Kh, u16* __restrict__ Vh)
{
    int idx = blockIdx.x * 256 + threadIdx.x;   // [0, 2*2048*16*32)
    int i = idx & 31;
    int h = (idx >> 5) & 15;
    int s = (idx >> 9) & 2047;
    int b = idx >> 20;
    float p = (float)pos[s];
    // angle = p * 10000^(-i/32) = p * 2^(-i/32 * log2(10000))
    float ang = p * exp2f((float)i * (-13.28771237954945f / 32.f));
    float cs = cosf(ang), sn = sinf(ang);
    size_t yb = ((size_t)(b * 2048 + s)) * 1024 + h * 64 + 2 * i;
    size_t ob = (((size_t)(b * 16 + h)) * 2048 + s) * 64 + 2 * i;
    float qe = b2f(Yq[yb]), qo = b2f(Yq[yb + 1]);
    float ke = b2f(Yk[yb]), ko = b2f(Yk[yb + 1]);
    Qh[ob]     = f2b(qe * cs - qo * sn);
    Qh[ob + 1] = f2b(qe * sn + qo * cs);
    Kh[ob]     = f2b(ke * cs - ko * sn);
    Kh[ob + 1] = f2b(ke * sn + ko * cs);
    Vh[ob]     = Yv[yb];
    Vh[ob + 1] = Yv[yb + 1];
}

// ---------------- Flash attention, causal, swapped-operand QK^T ----------------
// grid (S/64, B*H); 4 waves, wave w owns q-rows [w*16, w*16+16) of the 64-q tile
__global__ __launch_bounds__(256) void attn_kernel(
    const u16* __restrict__ Qh, const u16* __restrict__ Kh, const u16* __restrict__ Vh,
    u16* __restrict__ Oa)
{
    __shared__ u16 lsQ[64 * 64];
    __shared__ u16 lsK[64 * 64];
    __shared__ u16 lsVt[64 * 68];   // V^T, stride 68 (136B = 8B-aligned, bank-spread)
    const int tid = threadIdx.x;
    const int lane = tid & 63, wv = tid >> 6;
    const int l15 = lane & 15, lg = lane >> 4;
    const int qt = blockIdx.x, bh = blockIdx.y;
    const int b = bh >> 4, h = bh & 15;
    const u16* Qp = Qh + (size_t)bh * 2048 * 64;
    const u16* Kp = Kh + (size_t)bh * 2048 * 64;
    const u16* Vp = Vh + (size_t)bh * 2048 * 64;

#pragma unroll
    for (int r = 0; r < 2; ++r) {
        int c = r * 256 + tid;
        int row = c >> 3, col = (c & 7) << 3;
        gl16(Qp + (size_t)(qt * 64 + row) * 64 + col, &lsQ[(r * 256 + wv * 64) * 8]);
    }
    __syncthreads();
    bf16x8 qf[2];                   // Q as B-operand: n = q (=l15), k = d
#pragma unroll
    for (int ds = 0; ds < 2; ++ds)
        qf[ds] = ldfrag(&lsQ[(wv * 16 + l15) * 64 + ds * 32], lg);

    f32x4 accO[4];                  // O^T: row=d (within dm block), col=q
    for (int d = 0; d < 4; ++d)
        for (int r = 0; r < 4; ++r) accO[d][r] = 0.f;
    float mrun = -__builtin_inff(), lrun = 0.f;
    const int qglob = qt * 64 + wv * 16 + l15;

    for (int kt = 0; kt <= qt; ++kt) {
        __syncthreads();            // protect lsK/lsVt from prev-iter readers
#pragma unroll
        for (int r = 0; r < 2; ++r) {
            int c = r * 256 + tid;
            int row = c >> 3, col = (c & 7) << 3;
            gl16(Kp + (size_t)(kt * 64 + row) * 64 + col, &lsK[(r * 256 + wv * 64) * 8]);
        }
#pragma unroll
        for (int r = 0; r < 2; ++r) {
            int c = r * 256 + tid;
            int krow = c >> 3, dcol = (c & 7) << 3;
            ushort8 v = *(const ushort8*)(Vp + (size_t)(kt * 64 + krow) * 64 + dcol);
#pragma unroll
            for (int j = 0; j < 8; ++j) lsVt[(dcol + j) * 68 + krow] = v[j];
        }
        __syncthreads();
        // S^T[key][q] = K * Q^T, per 16-key block
        f32x4 sa[4];
#pragma unroll
        for (int kb = 0; kb < 4; ++kb) {
            bf16x8 kf0 = ldfrag(&lsK[(kb * 16 + l15) * 64], lg);
            bf16x8 kf1 = ldfrag(&lsK[(kb * 16 + l15) * 64 + 32], lg);
            f32x4 s;
            for (int r = 0; r < 4; ++r) s[r] = 0.f;
            s = __builtin_amdgcn_mfma_f32_16x16x32_bf16(kf0, qf[0], s, 0, 0, 0);
            s = __builtin_amdgcn_mfma_f32_16x16x32_bf16(kf1, qf[1], s, 0, 0, 0);
            sa[kb] = s;
        }
        float pv[4][4];
        float pm = -__builtin_inff();
#pragma unroll
        for (int kb = 0; kb < 4; ++kb)
#pragma unroll
            for (int r = 0; r < 4; ++r) {
                float sv = sa[kb][r] * 0.125f;
                int kg = kt * 64 + kb * 16 + lg * 4 + r;
                if (kg > qglob) sv = -__builtin_inff();   // causal
                pv[kb][r] = sv;
                pm = fmaxf(pm, sv);
            }
        pm = fmaxf(pm, __shfl_xor(pm, 16));
        pm = fmaxf(pm, __shfl_xor(pm, 32));
        float mnew = fmaxf(mrun, pm);
        float fac = exp2f((mrun - mnew) * LOG2E);
        float psum = 0.f;
#pragma unroll
        for (int kb = 0; kb < 4; ++kb)
#pragma unroll
            for (int r = 0; r < 4; ++r) {
                float pe = exp2f((pv[kb][r] - mnew) * LOG2E);
                pv[kb][r] = pe;
                psum += pe;
            }
        psum += __shfl_xor(psum, 16);
        psum += __shfl_xor(psum, 32);
        lrun = lrun * fac + psum;
        mrun = mnew;
#pragma unroll
        for (int d = 0; d < 4; ++d)
            for (int r = 0; r < 4; ++r) accO[d][r] *= fac;
        // P^T as B-operand: regs already hold [key][q] — no shuffles needed
        bf16x8 pf[2];
#pragma unroll
        for (int ks = 0; ks < 2; ++ks) {
            bf16x8 t;
#pragma unroll
            for (int j = 0; j < 4; ++j) {
                t[j]     = (__bf16)pv[2 * ks][j];
                t[4 + j] = (__bf16)pv[2 * ks + 1][j];
            }
            pf[ks] = t;
        }
#pragma unroll
        for (int dm = 0; dm < 4; ++dm)
#pragma unroll
            for (int ks = 0; ks < 2; ++ks) {
                bf16x8 vf = ldfrag(&lsVt[(dm * 16 + l15) * 68 + ks * 32], lg);
                accO[dm] = __builtin_amdgcn_mfma_f32_16x16x32_bf16(vf, pf[ks], accO[dm], 0, 0, 0);
            }
    }
    float inv = 1.f / lrun;
#pragma unroll
    for (int dm = 0; dm < 4; ++dm)
#pragma unroll
        for (int r = 0; r < 4; ++r) {
            int srow = qt * 64 + wv * 16 + l15;
            int e = h * 64 + dm * 16 + lg * 4 + r;
            Oa[((size_t)b * 2048 + srow) * 1024 + e] = f2b(accO[dm][r] * inv);
        }
}

extern "C" void kernel_launch(void* const* d_in, const int* in_sizes, int n_in,
                              void* d_out, int out_size, void* d_ws, size_t ws_size,
                              hipStream_t stream) {
    const float* x  = (const float*)d_in[0];
    const int*   pos = (const int*)d_in[1];
    const float* Wq = (const float*)d_in[2];
    const float* Wk = (const float*)d_in[3];
    const float* Wv = (const float*)d_in[4];
    const float* Wo = (const float*)d_in[5];
    float* out = (float*)d_out;
    char* ws = (char*)d_ws;
    const size_t MB = 1024 * 1024;
    u16* xb  = (u16*)(ws + 0);        //  8 MB  x bf16 (4096x1024)
    u16* wqb = (u16*)(ws + 8  * MB);  //  2 MB
    u16* wkb = (u16*)(ws + 10 * MB);
    u16* wvb = (u16*)(ws + 12 * MB);
    u16* wob = (u16*)(ws + 14 * MB);
    u16* Yq  = (u16*)(ws + 16 * MB);  //  8 MB each, (b,s,e)
    u16* Yk  = (u16*)(ws + 24 * MB);
    u16* Yv  = (u16*)(ws + 32 * MB);
    u16* Qh  = (u16*)(ws + 40 * MB);  //  8 MB each, (b,h,s,d)
    u16* Kh  = (u16*)(ws + 48 * MB);
    u16* Vh  = (u16*)(ws + 56 * MB);
    u16* Oa  = Yq;                    // reuse: Yq dead after rope

    cvt_kernel<<<4096, 256, 0, stream>>>(x,  xb,  1048576);
    cvt_kernel<<<1024, 256, 0, stream>>>(Wq, wqb, 262144);
    cvt_kernel<<<1024, 256, 0, stream>>>(Wk, wkb, 262144);
    cvt_kernel<<<1024, 256, 0, stream>>>(Wv, wvb, 262144);
    cvt_kernel<<<1024, 256, 0, stream>>>(Wo, wob, 262144);

    dim3 g(8, 32);   // (N/128, M/128)
    gemm_bt<<<g, 256, 0, stream>>>(xb, wqb, nullptr, Yq, 4096, 1024, 1024);
    gemm_bt<<<g, 256, 0, stream>>>(xb, wkb, nullptr, Yk, 4096, 1024, 1024);
    gemm_bt<<<g, 256, 0, stream>>>(xb, wvb, nullptr, Yv, 4096, 1024, 1024);

    rope_kernel<<<8192, 256, 0, stream>>>(Yq, Yk, Yv, pos, Qh, Kh, Vh);

    attn_kernel<<<dim3(32, 32), 256, 0, stream>>>(Qh, Kh, Vh, Oa);

    gemm_bt<<<g, 256, 0, stream>>>(Oa, wob, out, nullptr, 4096, 1024, 1024);
}

// Round 2
// 207.656 us; speedup vs baseline: 2.4508x; 2.4508x over previous
//
#include <hip/hip_runtime.h>
#include <hip/hip_bf16.h>
#include <math.h>

typedef __attribute__((ext_vector_type(4))) float   f32x4;
typedef __attribute__((ext_vector_type(4))) __bf16  bf16x4;
typedef __attribute__((ext_vector_type(8))) __bf16  bf16x8;
typedef __attribute__((ext_vector_type(8))) unsigned short ushort8;
typedef unsigned short u16;

#define LOG2E 1.44269504088896f

__device__ __forceinline__ u16 f2b(float f) {
    unsigned u = __builtin_bit_cast(unsigned, f);
    u += 0x7fff + ((u >> 16) & 1);          // RNE
    return (u16)(u >> 16);
}
__device__ __forceinline__ float b2f(u16 h) {
    unsigned u = ((unsigned)h) << 16;
    return __builtin_bit_cast(float, u);
}
// async global->LDS, 16B per lane; LDS dest = wave-uniform base + lane*16
__device__ __forceinline__ void gl16(const void* g, void* l) {
    __builtin_amdgcn_global_load_lds((const __attribute__((address_space(1))) void*)g,
                                     (__attribute__((address_space(3))) void*)l, 16, 0, 0);
}

// ---- swizzled fragment loads (16x16x32 bf16 operand) ----
// 128B-row tiles (64 u16/row): swizzle u16-idx ^= (row&7)<<3  (byte<<4)
__device__ __forceinline__ bf16x8 ldfA(const u16* base, int row, int col0, int lg) {
    const u16* rp = base + row * 64;
    const int sw = (row & 7) << 3;
    bf16x4 lo = *(const bf16x4*)(rp + ((col0 + lg * 4) ^ sw));
    bf16x4 hi = *(const bf16x4*)(rp + ((col0 + 16 + lg * 4) ^ sw));
    return __builtin_shufflevector(lo, hi, 0, 1, 2, 3, 4, 5, 6, 7);
}
// 64B-row tiles (32 u16/row): swizzle u16-idx ^= ((row>>1)&3)<<3 (byte<<4)
__device__ __forceinline__ bf16x8 ldfG(const u16* base, int row, int lg) {
    const u16* rp = base + row * 32;
    const int sw = ((row >> 1) & 3) << 3;
    bf16x4 lo = *(const bf16x4*)(rp + ((lg * 4) ^ sw));
    bf16x4 hi = *(const bf16x4*)(rp + ((16 + lg * 4) ^ sw));
    return __builtin_shufflevector(lo, hi, 0, 1, 2, 3, 4, 5, 6, 7);
}

// ---------------- f32 -> bf16 convert ----------------
__global__ void cvt_kernel(const float* __restrict__ src, u16* __restrict__ dst, int n4) {
    int i = blockIdx.x * 256 + threadIdx.x;
    if (i < n4) {
        float4 v = ((const float4*)src)[i];
        ushort4 o = make_ushort4(f2b(v.x), f2b(v.y), f2b(v.z), f2b(v.w));
        ((ushort4*)dst)[i] = o;
    }
}

// ---------------- GEMM: C[M,N] = A[M,K] * Bw[N,K]^T (bf16 in, f32 acc) ----------------
// 128x128 tile, BK=32, 4 waves in 2x2, each wave 64x64 (4x4 fragments)
// LDS tiles stored with the ldfG swizzle; global source pre-permuted to match.
__global__ __launch_bounds__(256) void gemm_bt(
    const u16* __restrict__ A, const u16* __restrict__ Bw,
    float* __restrict__ Cf, u16* __restrict__ Cb, int M, int N, int K)
{
    __shared__ u16 lsA[128 * 32];
    __shared__ u16 lsB[128 * 32];
    const int tid = threadIdx.x;
    const int lane = tid & 63, wv = tid >> 6;
    const int l15 = lane & 15, lg = lane >> 4;
    const int mblk = blockIdx.y * 128, nblk = blockIdx.x * 128;
    const int m0 = (wv >> 1) * 64, n0 = (wv & 1) * 64;

    f32x4 acc[4][4];
    for (int a = 0; a < 4; ++a)
        for (int b = 0; b < 4; ++b)
            for (int r = 0; r < 4; ++r) acc[a][b][r] = 0.f;

    for (int kt = 0; kt < K; kt += 32) {
#pragma unroll
        for (int r = 0; r < 2; ++r) {
            int c = r * 256 + tid;           // 16B chunk id
            int row = c >> 2;
            int col = ((c & 3) << 3) ^ (((row >> 1) & 3) << 3);  // inverse-swizzled source col
            gl16(A  + (size_t)(mblk + row) * K + kt + col, &lsA[(r * 256 + wv * 64) * 8]);
            gl16(Bw + (size_t)(nblk + row) * K + kt + col, &lsB[(r * 256 + wv * 64) * 8]);
        }
        __syncthreads();
        bf16x8 af[4], bfr[4];
#pragma unroll
        for (int mm = 0; mm < 4; ++mm) af[mm] = ldfG(lsA, m0 + mm * 16 + l15, lg);
#pragma unroll
        for (int nn = 0; nn < 4; ++nn) bfr[nn] = ldfG(lsB, n0 + nn * 16 + l15, lg);
#pragma unroll
        for (int mm = 0; mm < 4; ++mm)
#pragma unroll
            for (int nn = 0; nn < 4; ++nn)
                acc[mm][nn] = __builtin_amdgcn_mfma_f32_16x16x32_bf16(af[mm], bfr[nn], acc[mm][nn], 0, 0, 0);
        __syncthreads();
    }
    // C/D layout: col = lane&15, row = (lane>>4)*4 + reg
#pragma unroll
    for (int mm = 0; mm < 4; ++mm)
#pragma unroll
        for (int nn = 0; nn < 4; ++nn)
#pragma unroll
            for (int r = 0; r < 4; ++r) {
                int row = mblk + m0 + mm * 16 + lg * 4 + r;
                int col = nblk + n0 + nn * 16 + l15;
                float v = acc[mm][nn][r];
                if (Cf) Cf[(size_t)row * N + col] = v;
                else    Cb[(size_t)row * N + col] = f2b(v);
            }
}

// ---------------- RoPE + relayout (b,s,3072) -> Qh,Kh (b,h,s,d) ----------------
__global__ void rope_kernel(const u16* __restrict__ Y, const int* __restrict__ pos,
                            u16* __restrict__ Qh, u16* __restrict__ Kh)
{
    int idx = blockIdx.x * 256 + threadIdx.x;   // [0, 2*2048*16*32)
    int i = idx & 31;
    int h = (idx >> 5) & 15;
    int s = (idx >> 9) & 2047;
    int b = idx >> 20;
    float p = (float)pos[s];
    float ang = p * exp2f((float)i * (-13.28771237954945f / 32.f));
    float cs = cosf(ang), sn = sinf(ang);
    size_t yb = ((size_t)(b * 2048 + s)) * 3072 + h * 64 + 2 * i;
    size_t ob = (((size_t)(b * 16 + h)) * 2048 + s) * 64 + 2 * i;
    float qe = b2f(Y[yb]), qo = b2f(Y[yb + 1]);
    float ke = b2f(Y[yb + 1024]), ko = b2f(Y[yb + 1025]);
    Qh[ob]     = f2b(qe * cs - qo * sn);
    Qh[ob + 1] = f2b(qe * sn + qo * cs);
    Kh[ob]     = f2b(ke * cs - ko * sn);
    Kh[ob + 1] = f2b(ke * sn + ko * cs);
}

// ---------------- V transpose: Y(b,s,2048+h*64+d) -> Vt (b,h,d,s) ----------------
__global__ __launch_bounds__(256) void vtrans_kernel(const u16* __restrict__ Y, u16* __restrict__ Vt)
{
    __shared__ u16 t[64][72];
    const int st = blockIdx.x, bh = blockIdx.y;
    const int b = bh >> 4, h = bh & 15;
    const int tid = threadIdx.x;
    {
        int s = tid >> 2, dc = (tid & 3) << 4;
        const u16* src = Y + ((size_t)(b * 2048 + st * 64 + s)) * 3072 + 2048 + h * 64 + dc;
        ushort8 v0 = *(const ushort8*)src;
        ushort8 v1 = *(const ushort8*)(src + 8);
#pragma unroll
        for (int j = 0; j < 8; ++j) { t[dc + j][s] = v0[j]; t[dc + 8 + j][s] = v1[j]; }
    }
    __syncthreads();
    {
        int d = tid >> 2, sc = (tid & 3) << 4;
        ushort8 w0 = *(const ushort8*)(&t[d][sc]);
        ushort8 w1 = *(const ushort8*)(&t[d][sc + 8]);
        u16* dst = Vt + ((size_t)bh * 64 + d) * 2048 + st * 64 + sc;
        *(ushort8*)dst = w0;
        *(ushort8*)(dst + 8) = w1;
    }
}

// ---------------- Flash attention, causal, swapped-operand QK^T ----------------
// grid (S/64, B*H); 4 waves, wave w owns q-rows [w*16, w*16+16) of the 64-q tile
// K tile: (key, d) rows of 128B; Vt tile: (d, key) rows of 128B; both XOR-swizzled.
__global__ __launch_bounds__(256) void attn_kernel(
    const u16* __restrict__ Qh, const u16* __restrict__ Kh, const u16* __restrict__ Vt,
    u16* __restrict__ Oa)
{
    __shared__ u16 lsQ[64 * 64];
    __shared__ u16 lsK[64 * 64];
    __shared__ u16 lsV[64 * 64];
    const int tid = threadIdx.x;
    const int lane = tid & 63, wv = tid >> 6;
    const int l15 = lane & 15, lg = lane >> 4;
    const int qt = blockIdx.x, bh = blockIdx.y;
    const int b = bh >> 4, h = bh & 15;
    const u16* Qp = Qh + (size_t)bh * 2048 * 64;
    const u16* Kp = Kh + (size_t)bh * 2048 * 64;
    const u16* Vp = Vt + (size_t)bh * 64 * 2048;

#pragma unroll
    for (int r = 0; r < 2; ++r) {
        int c = r * 256 + tid;
        int row = c >> 3;
        int col = ((c & 7) << 3) ^ ((row & 7) << 3);
        gl16(Qp + (size_t)(qt * 64 + row) * 64 + col, &lsQ[(r * 256 + wv * 64) * 8]);
    }
    __syncthreads();
    bf16x8 qf[2];                   // Q as B-operand: n = q (=l15), k = d
#pragma unroll
    for (int ds = 0; ds < 2; ++ds)
        qf[ds] = ldfA(lsQ, wv * 16 + l15, ds * 32, lg);

    f32x4 accO[4];                  // O^T: row=d (within dm block), col=q
    for (int d = 0; d < 4; ++d)
        for (int r = 0; r < 4; ++r) accO[d][r] = 0.f;
    float mrun = -__builtin_inff(), lrun = 0.f;
    const int qglob = qt * 64 + wv * 16 + l15;

    for (int kt = 0; kt <= qt; ++kt) {
        __syncthreads();            // protect lsK/lsV from prev-iter readers
#pragma unroll
        for (int r = 0; r < 2; ++r) {
            int c = r * 256 + tid;
            int row = c >> 3;
            int col = ((c & 7) << 3) ^ ((row & 7) << 3);
            gl16(Kp + (size_t)(kt * 64 + row) * 64 + col, &lsK[(r * 256 + wv * 64) * 8]);
            gl16(Vp + (size_t)row * 2048 + kt * 64 + col, &lsV[(r * 256 + wv * 64) * 8]);
        }
        __syncthreads();
        // S^T[key][q] = K * Q^T, per 16-key block
        f32x4 sa[4];
#pragma unroll
        for (int kb = 0; kb < 4; ++kb) {
            bf16x8 kf0 = ldfA(lsK, kb * 16 + l15, 0, lg);
            bf16x8 kf1 = ldfA(lsK, kb * 16 + l15, 32, lg);
            f32x4 s;
            for (int r = 0; r < 4; ++r) s[r] = 0.f;
            s = __builtin_amdgcn_mfma_f32_16x16x32_bf16(kf0, qf[0], s, 0, 0, 0);
            s = __builtin_amdgcn_mfma_f32_16x16x32_bf16(kf1, qf[1], s, 0, 0, 0);
            sa[kb] = s;
        }
        float pv[4][4];
        float pm = -__builtin_inff();
#pragma unroll
        for (int kb = 0; kb < 4; ++kb)
#pragma unroll
            for (int r = 0; r < 4; ++r) {
                float sv = sa[kb][r] * 0.125f;
                int kg = kt * 64 + kb * 16 + lg * 4 + r;
                if (kg > qglob) sv = -__builtin_inff();   // causal
                pv[kb][r] = sv;
                pm = fmaxf(pm, sv);
            }
        pm = fmaxf(pm, __shfl_xor(pm, 16));
        pm = fmaxf(pm, __shfl_xor(pm, 32));
        float mnew = fmaxf(mrun, pm);
        float fac = exp2f((mrun - mnew) * LOG2E);
        float psum = 0.f;
#pragma unroll
        for (int kb = 0; kb < 4; ++kb)
#pragma unroll
            for (int r = 0; r < 4; ++r) {
                float pe = exp2f((pv[kb][r] - mnew) * LOG2E);
                pv[kb][r] = pe;
                psum += pe;
            }
        psum += __shfl_xor(psum, 16);
        psum += __shfl_xor(psum, 32);
        lrun = lrun * fac + psum;
        mrun = mnew;
#pragma unroll
        for (int d = 0; d < 4; ++d)
            for (int r = 0; r < 4; ++r) accO[d][r] *= fac;
        // P^T as B-operand: regs already hold [key][q] — no shuffles needed
        bf16x8 pf[2];
#pragma unroll
        for (int ks = 0; ks < 2; ++ks) {
            bf16x8 t;
#pragma unroll
            for (int j = 0; j < 4; ++j) {
                t[j]     = (__bf16)pv[2 * ks][j];
                t[4 + j] = (__bf16)pv[2 * ks + 1][j];
            }
            pf[ks] = t;
        }
#pragma unroll
        for (int dm = 0; dm < 4; ++dm)
#pragma unroll
            for (int ks = 0; ks < 2; ++ks) {
                bf16x8 vf = ldfA(lsV, dm * 16 + l15, ks * 32, lg);
                accO[dm] = __builtin_amdgcn_mfma_f32_16x16x32_bf16(vf, pf[ks], accO[dm], 0, 0, 0);
            }
    }
    float inv = 1.f / lrun;
#pragma unroll
    for (int dm = 0; dm < 4; ++dm)
#pragma unroll
        for (int r = 0; r < 4; ++r) {
            int srow = qt * 64 + wv * 16 + l15;
            int e = h * 64 + dm * 16 + lg * 4 + r;
            Oa[((size_t)b * 2048 + srow) * 1024 + e] = f2b(accO[dm][r] * inv);
        }
}

extern "C" void kernel_launch(void* const* d_in, const int* in_sizes, int n_in,
                              void* d_out, int out_size, void* d_ws, size_t ws_size,
                              hipStream_t stream) {
    const float* x  = (const float*)d_in[0];
    const int*   pos = (const int*)d_in[1];
    const float* Wq = (const float*)d_in[2];
    const float* Wk = (const float*)d_in[3];
    const float* Wv = (const float*)d_in[4];
    const float* Wo = (const float*)d_in[5];
    float* out = (float*)d_out;
    char* ws = (char*)d_ws;
    const size_t MB = 1024 * 1024;
    u16* xb   = (u16*)(ws + 0);         //  8 MB  x bf16 (4096x1024)
    u16* wqkv = (u16*)(ws + 8  * MB);   //  6 MB  fused [Wq;Wk;Wv] (3072x1024)
    u16* wob  = (u16*)(ws + 14 * MB);   //  2 MB
    u16* Yqkv = (u16*)(ws + 16 * MB);   // 24 MB  (b,s,3072)
    u16* Qh   = (u16*)(ws + 40 * MB);   //  8 MB  (b,h,s,d)
    u16* Kh   = (u16*)(ws + 48 * MB);
    u16* Vt   = (u16*)(ws + 56 * MB);   //  8 MB  (b,h,d,s)
    u16* Oa   = Yqkv;                   // reuse: Yqkv dead after rope+vtrans

    cvt_kernel<<<4096, 256, 0, stream>>>(x,  xb, 1048576);
    cvt_kernel<<<1024, 256, 0, stream>>>(Wq, wqkv,              262144);
    cvt_kernel<<<1024, 256, 0, stream>>>(Wk, wqkv + 1024 * 1024, 262144);
    cvt_kernel<<<1024, 256, 0, stream>>>(Wv, wqkv + 2048 * 1024, 262144);
    cvt_kernel<<<1024, 256, 0, stream>>>(Wo, wob, 262144);

    // fused QKV projection: (4096x1024) x (3072x1024)^T
    gemm_bt<<<dim3(24, 32), 256, 0, stream>>>(xb, wqkv, nullptr, Yqkv, 4096, 3072, 1024);

    rope_kernel<<<8192, 256, 0, stream>>>(Yqkv, pos, Qh, Kh);
    vtrans_kernel<<<dim3(32, 32), 256, 0, stream>>>(Yqkv, Vt);

    attn_kernel<<<dim3(32, 32), 256, 0, stream>>>(Qh, Kh, Vt, Oa);

    // out projection -> f32
    gemm_bt<<<dim3(8, 32), 256, 0, stream>>>(Oa, wob, out, nullptr, 4096, 1024, 1024);
}

// Round 4
// 153.854 us; speedup vs baseline: 3.3079x; 1.3497x over previous
//
#include <hip/hip_runtime.h>
#include <hip/hip_bf16.h>
#include <math.h>

typedef __attribute__((ext_vector_type(4))) float   f32x4;
typedef __attribute__((ext_vector_type(8))) __bf16  bf16x8;
typedef __attribute__((ext_vector_type(8))) unsigned short ushort8;
typedef unsigned short u16;

#define QSCALE 0.1803368801111729f   // 0.125 * log2(e): softmax done in exp2 domain

__device__ __forceinline__ u16 f2b(float f) {
    unsigned u = __builtin_bit_cast(unsigned, f);
    u += 0x7fff + ((u >> 16) & 1);          // RNE
    return (u16)(u >> 16);
}
__device__ __forceinline__ float b2f(u16 h) {
    unsigned u = ((unsigned)h) << 16;
    return __builtin_bit_cast(float, u);
}
// async global->LDS, 16B per lane; LDS dest = wave-uniform base + lane*16
__device__ __forceinline__ void gl16(const void* g, void* l) {
    __builtin_amdgcn_global_load_lds((const __attribute__((address_space(1))) void*)g,
                                     (__attribute__((address_space(3))) void*)l, 16, 0, 0);
}
// k-permutation within a 32-elem chunk: dim d stored at pos32(d). Constructed so
// that MFMA frag element j (hw k = (j>>2)*16 + lg*4 + (j&3)) is CONTIGUOUS 16B.
__device__ __forceinline__ int pos32(int d) {
    return ((d & 15) >> 2) * 8 + ((d >> 4) & 1) * 4 + (d & 3);
}
// single ds_read_b128 fragment from a 64-col permuted+swizzled LDS tile
__device__ __forceinline__ bf16x8 frag128(const u16* tile, int row, int half, int lg) {
    int gran = (half * 4 + lg) ^ (row & 7);
    return *(const bf16x8*)(tile + row * 64 + gran * 8);
}

// ---------------- f32 -> bf16 convert ----------------
__global__ void cvt_kernel(const float* __restrict__ src, u16* __restrict__ dst, int n4) {
    int i = blockIdx.x * 256 + threadIdx.x;
    if (i < n4) {
        float4 v = ((const float4*)src)[i];
        ((ushort4*)dst)[i] = make_ushort4(f2b(v.x), f2b(v.y), f2b(v.z), f2b(v.w));
    }
}
__global__ void cvtw_kernel(const float* __restrict__ s0, const float* __restrict__ s1,
                            const float* __restrict__ s2, const float* __restrict__ s3,
                            u16* __restrict__ d0, u16* __restrict__ d1,
                            u16* __restrict__ d2, u16* __restrict__ d3) {
    int i = blockIdx.x * 256 + threadIdx.x;      // [0, 262144) float4s per weight
    int w = blockIdx.y;
    const float* s = (w == 0) ? s0 : (w == 1) ? s1 : (w == 2) ? s2 : s3;
    u16* d        = (w == 0) ? d0 : (w == 1) ? d1 : (w == 2) ? d2 : d3;
    float4 v = ((const float4*)s)[i];
    ((ushort4*)d)[i] = make_ushort4(f2b(v.x), f2b(v.y), f2b(v.z), f2b(v.w));
}

// ---------------- GEMM: C[M,N] = A[M,K] * Bw[N,K]^T, 2-phase double-buffered ----------------
__device__ __forceinline__ bf16x8 ldfG(const u16* tile, int row, int lg) {
    const u16* rp = tile + row * 32;
    const int sw = ((row >> 1) & 3) << 3;
    typedef __attribute__((ext_vector_type(4))) __bf16 bf16x4;
    bf16x4 lo = *(const bf16x4*)(rp + ((lg * 4) ^ sw));
    bf16x4 hi = *(const bf16x4*)(rp + ((16 + lg * 4) ^ sw));
    return __builtin_shufflevector(lo, hi, 0, 1, 2, 3, 4, 5, 6, 7);
}
__global__ __launch_bounds__(256) void gemm_bt(
    const u16* __restrict__ A, const u16* __restrict__ Bw,
    float* __restrict__ Cf, u16* __restrict__ Cb, int M, int N, int K)
{
    __shared__ u16 lsA[2][128 * 32];
    __shared__ u16 lsB[2][128 * 32];
    const int tid = threadIdx.x;
    const int lane = tid & 63, wv = tid >> 6;
    const int l15 = lane & 15, lg = lane >> 4;
    const int mblk = blockIdx.y * 128, nblk = blockIdx.x * 128;
    const int m0 = (wv >> 1) * 64, n0 = (wv & 1) * 64;
    const int NIT = K >> 5;

    f32x4 acc[4][4];
    for (int a = 0; a < 4; ++a)
        for (int b = 0; b < 4; ++b)
            for (int r = 0; r < 4; ++r) acc[a][b][r] = 0.f;

    // prologue: stage tile 0 -> buf 0
#pragma unroll
    for (int r = 0; r < 2; ++r) {
        int c = r * 256 + tid;
        int row = c >> 2;
        int col = ((c & 3) << 3) ^ (((row >> 1) & 3) << 3);
        gl16(A  + (size_t)(mblk + row) * K + col, &lsA[0][(r * 256 + wv * 64) * 8]);
        gl16(Bw + (size_t)(nblk + row) * K + col, &lsB[0][(r * 256 + wv * 64) * 8]);
    }
    for (int it = 0; it < NIT; ++it) {
        const int cur = it & 1;
        __syncthreads();                     // buf[cur] ready; prev reads of buf[cur^1] done
        if (it + 1 < NIT) {
            const int kt = (it + 1) << 5;
#pragma unroll
            for (int r = 0; r < 2; ++r) {
                int c = r * 256 + tid;
                int row = c >> 2;
                int col = ((c & 3) << 3) ^ (((row >> 1) & 3) << 3);
                gl16(A  + (size_t)(mblk + row) * K + kt + col, &lsA[cur ^ 1][(r * 256 + wv * 64) * 8]);
                gl16(Bw + (size_t)(nblk + row) * K + kt + col, &lsB[cur ^ 1][(r * 256 + wv * 64) * 8]);
            }
        }
        bf16x8 af[4], bfr[4];
#pragma unroll
        for (int mm = 0; mm < 4; ++mm) af[mm] = ldfG(lsA[cur], m0 + mm * 16 + l15, lg);
#pragma unroll
        for (int nn = 0; nn < 4; ++nn) bfr[nn] = ldfG(lsB[cur], n0 + nn * 16 + l15, lg);
#pragma unroll
        for (int mm = 0; mm < 4; ++mm)
#pragma unroll
            for (int nn = 0; nn < 4; ++nn)
                acc[mm][nn] = __builtin_amdgcn_mfma_f32_16x16x32_bf16(af[mm], bfr[nn], acc[mm][nn], 0, 0, 0);
    }
#pragma unroll
    for (int mm = 0; mm < 4; ++mm)
#pragma unroll
        for (int nn = 0; nn < 4; ++nn)
#pragma unroll
            for (int r = 0; r < 4; ++r) {
                int row = mblk + m0 + mm * 16 + lg * 4 + r;
                int col = nblk + n0 + nn * 16 + l15;
                float v = acc[mm][nn][r];
                if (Cf) Cf[(size_t)row * N + col] = v;
                else    Cb[(size_t)row * N + col] = f2b(v);
            }
}

// ---------------- RoPE + relayout (b,s,3072) -> Qh,Kh (b,h,s,d') with permuted d ----------------
// Qh additionally pre-scaled by QSCALE (softmax scale folded, exp2 domain)
__global__ void rope_kernel(const u16* __restrict__ Y, const int* __restrict__ pos,
                            u16* __restrict__ Qh, u16* __restrict__ Kh)
{
    int idx = blockIdx.x * 256 + threadIdx.x;   // [0, 2*2048*16*32)
    int i = idx & 31;
    int h = (idx >> 5) & 15;
    int s = (idx >> 9) & 2047;
    int b = idx >> 20;
    float p = (float)pos[s];
    float ang = p * exp2f((float)i * (-13.28771237954945f / 32.f));
    float cs = cosf(ang), sn = sinf(ang);
    size_t yb = ((size_t)(b * 2048 + s)) * 3072 + h * 64 + 2 * i;
    int d = 2 * i;
    int outd = (d & 32) + pos32(d & 31);        // d even -> outd,outd+1 adjacent
    size_t ob = (((size_t)(b * 16 + h)) * 2048 + s) * 64 + outd;
    float qe = b2f(Y[yb]), qo = b2f(Y[yb + 1]);
    float ke = b2f(Y[yb + 1024]), ko = b2f(Y[yb + 1025]);
    Qh[ob]     = f2b((qe * cs - qo * sn) * QSCALE);
    Qh[ob + 1] = f2b((qe * sn + qo * cs) * QSCALE);
    Kh[ob]     = f2b(ke * cs - ko * sn);
    Kh[ob + 1] = f2b(ke * sn + ko * cs);
}

// ---------------- V transpose: Y(b,s,2048+h*64+d) -> Vt (b,h,d,s') with permuted s ----------------
__global__ __launch_bounds__(256) void vtrans_kernel(const u16* __restrict__ Y, u16* __restrict__ Vt)
{
    __shared__ u16 t[64][72];
    const int st = blockIdx.x, bh = blockIdx.y;
    const int b = bh >> 4, h = bh & 15;
    const int tid = threadIdx.x;
    {
        int s = tid >> 2, dc = (tid & 3) << 4;
        const u16* src = Y + ((size_t)(b * 2048 + st * 64 + s)) * 3072 + 2048 + h * 64 + dc;
        ushort8 v0 = *(const ushort8*)src;
        ushort8 v1 = *(const ushort8*)(src + 8);
#pragma unroll
        for (int j = 0; j < 8; ++j) { t[dc + j][s] = v0[j]; t[dc + 8 + j][s] = v1[j]; }
    }
    __syncthreads();
    {
        int d = tid >> 2, sc = (tid & 3) << 4;
        int chunk = sc & 32, h4 = (sc >> 4) & 1;
        u16* dst = Vt + ((size_t)bh * 64 + d) * 2048 + st * 64 + chunk + h4 * 4;
#pragma unroll
        for (int a = 0; a < 4; ++a) {
            ushort4 w = make_ushort4(t[d][sc + 4 * a], t[d][sc + 4 * a + 1],
                                     t[d][sc + 4 * a + 2], t[d][sc + 4 * a + 3]);
            *(ushort4*)(dst + a * 8) = w;    // pos(s32)=a*8+h4*4+j
        }
    }
}

// ---------------- Flash attention: QBLK=128, KVBLK=64, dbuf, causal-split, defer-max ----------------
__device__ __forceinline__ void stage_kv(const u16* Kp, const u16* Vp, int kt,
                                         u16* bK, u16* bV, int tid, int wv) {
#pragma unroll
    for (int r = 0; r < 2; ++r) {
        int c = r * 256 + tid;
        int row = c >> 3;
        int col = ((c & 7) ^ (row & 7)) * 8;
        gl16(Kp + (size_t)(kt * 64 + row) * 64 + col, bK + (r * 256 + wv * 64) * 8);
        gl16(Vp + (size_t)row * 2048 + kt * 64 + col, bV + (r * 256 + wv * 64) * 8);
    }
}
__global__ __launch_bounds__(256) void attn_kernel(
    const u16* __restrict__ Qh, const u16* __restrict__ Kh, const u16* __restrict__ Vt,
    u16* __restrict__ Oa)
{
    __shared__ u16 lsQ[128 * 64];
    __shared__ u16 lsK[2][64 * 64];
    __shared__ u16 lsV[2][64 * 64];
    const int tid = threadIdx.x;
    const int lane = tid & 63, wv = tid >> 6;
    const int l15 = lane & 15, lg = lane >> 4;
    // paired heavy+light mapping: ids [0,256) -> qt 15..8, [256,512) -> qt 0..7 (work-balanced)
    const int id = blockIdx.x;
    const int gq = id >> 5;
    const int qt = (id < 256) ? (15 - gq) : (gq - 8);
    const int bh = id & 31;
    const int b = bh >> 4, h = bh & 15;
    const u16* Qp = Qh + (size_t)bh * 2048 * 64;
    const u16* Kp = Kh + (size_t)bh * 2048 * 64;
    const u16* Vp = Vt + (size_t)bh * 64 * 2048;

    // stage Q (128 rows)
#pragma unroll
    for (int r = 0; r < 4; ++r) {
        int c = r * 256 + tid;
        int row = c >> 3;
        int col = ((c & 7) ^ (row & 7)) * 8;
        gl16(Qp + (size_t)(qt * 128 + row) * 64 + col, &lsQ[(r * 256 + wv * 64) * 8]);
    }
    stage_kv(Kp, Vp, 0, lsK[0], lsV[0], tid, wv);
    __syncthreads();

    bf16x8 qf[2][2];
#pragma unroll
    for (int m = 0; m < 2; ++m)
#pragma unroll
        for (int ds = 0; ds < 2; ++ds)
            qf[m][ds] = frag128(lsQ, wv * 32 + m * 16 + l15, ds, lg);

    f32x4 accO[2][4];
#pragma unroll
    for (int m = 0; m < 2; ++m)
        for (int dm = 0; dm < 4; ++dm)
            for (int r = 0; r < 4; ++r) accO[m][dm][r] = 0.f;
    float mrun[2] = { -3e38f, -3e38f }, lrun[2] = { 0.f, 0.f };
    const int nfull = 2 * qt + (wv >> 1);     // tiles [0,nfull) unmasked; nfull = boundary
    const int NT = 2 * qt + 2;

    for (int kt = 0; kt < NT; ++kt) {
        const int cur = kt & 1;
        if (kt + 1 < NT)
            stage_kv(Kp, Vp, kt + 1, lsK[cur ^ 1], lsV[cur ^ 1], tid, wv);
        if (kt <= nfull) {
            f32x4 sa[2][4];
#pragma unroll
            for (int kb = 0; kb < 4; ++kb) {
                int krow = kb * 16 + l15;
                bf16x8 kf0 = frag128(lsK[cur], krow, 0, lg);
                bf16x8 kf1 = frag128(lsK[cur], krow, 1, lg);
#pragma unroll
                for (int m = 0; m < 2; ++m) {
                    f32x4 s = { 0.f, 0.f, 0.f, 0.f };
                    s = __builtin_amdgcn_mfma_f32_16x16x32_bf16(kf0, qf[m][0], s, 0, 0, 0);
                    s = __builtin_amdgcn_mfma_f32_16x16x32_bf16(kf1, qf[m][1], s, 0, 0, 0);
                    sa[m][kb] = s;
                }
            }
            if (kt == nfull) {                 // only the boundary tile pays mask VALU
#pragma unroll
                for (int m = 0; m < 2; ++m) {
                    int qg = qt * 128 + wv * 32 + m * 16 + l15;
#pragma unroll
                    for (int kb = 0; kb < 4; ++kb)
#pragma unroll
                        for (int r = 0; r < 4; ++r)
                            if (kt * 64 + kb * 16 + lg * 4 + r > qg) sa[m][kb][r] = -1e30f;
                }
            }
            float pm[2];
#pragma unroll
            for (int m = 0; m < 2; ++m) {
                float a = fmaxf(fmaxf(sa[m][0][0], sa[m][0][1]), fmaxf(sa[m][0][2], sa[m][0][3]));
                float c = fmaxf(fmaxf(sa[m][1][0], sa[m][1][1]), fmaxf(sa[m][1][2], sa[m][1][3]));
                float d = fmaxf(fmaxf(sa[m][2][0], sa[m][2][1]), fmaxf(sa[m][2][2], sa[m][2][3]));
                float e = fmaxf(fmaxf(sa[m][3][0], sa[m][3][1]), fmaxf(sa[m][3][2], sa[m][3][3]));
                float x = fmaxf(fmaxf(a, c), fmaxf(d, e));
                x = fmaxf(x, __shfl_xor(x, 16));
                x = fmaxf(x, __shfl_xor(x, 32));
                pm[m] = x;
            }
            // T13 defer-max: skip rescale when tile max is within 8 (exp2 units) of running max
            bool near = (pm[0] <= mrun[0] + 8.f) && (pm[1] <= mrun[1] + 8.f);
            if (!__all(near)) {
#pragma unroll
                for (int m = 0; m < 2; ++m) {
                    float mnew = fmaxf(mrun[m], pm[m]);
                    float fac = exp2f(mrun[m] - mnew);
                    lrun[m] *= fac;
#pragma unroll
                    for (int dm = 0; dm < 4; ++dm)
#pragma unroll
                        for (int r = 0; r < 4; ++r) accO[m][dm][r] *= fac;
                    mrun[m] = mnew;
                }
            }
            float ps[2] = { 0.f, 0.f };
#pragma unroll
            for (int m = 0; m < 2; ++m)
#pragma unroll
                for (int kb = 0; kb < 4; ++kb)
#pragma unroll
                    for (int r = 0; r < 4; ++r) {
                        float pe = exp2f(sa[m][kb][r] - mrun[m]);
                        sa[m][kb][r] = pe;
                        ps[m] += pe;
                    }
#pragma unroll
            for (int m = 0; m < 2; ++m) {
                float x = ps[m];
                x += __shfl_xor(x, 16);
                x += __shfl_xor(x, 32);
                lrun[m] += x;
            }
            bf16x8 pf[2][2];
#pragma unroll
            for (int m = 0; m < 2; ++m)
#pragma unroll
                for (int ks = 0; ks < 2; ++ks) {
                    bf16x8 t;
#pragma unroll
                    for (int j = 0; j < 4; ++j) {
                        t[j]     = (__bf16)sa[m][2 * ks][j];
                        t[4 + j] = (__bf16)sa[m][2 * ks + 1][j];
                    }
                    pf[m][ks] = t;
                }
#pragma unroll
            for (int dm = 0; dm < 4; ++dm) {
                int vrow = dm * 16 + l15;
#pragma unroll
                for (int ks = 0; ks < 2; ++ks) {
                    bf16x8 vf = frag128(lsV[cur], vrow, ks, lg);
#pragma unroll
                    for (int m = 0; m < 2; ++m)
                        accO[m][dm] = __builtin_amdgcn_mfma_f32_16x16x32_bf16(vf, pf[m][ks], accO[m][dm], 0, 0, 0);
                }
            }
        }
        __syncthreads();                       // next tile staged + this tile's reads done
    }
#pragma unroll
    for (int m = 0; m < 2; ++m) {
        float inv = 1.f / lrun[m];
        int srow = qt * 128 + wv * 32 + m * 16 + l15;
#pragma unroll
        for (int dm = 0; dm < 4; ++dm) {
            ushort4 o = make_ushort4(f2b(accO[m][dm][0] * inv), f2b(accO[m][dm][1] * inv),
                                     f2b(accO[m][dm][2] * inv), f2b(accO[m][dm][3] * inv));
            *(ushort4*)&Oa[((size_t)b * 2048 + srow) * 1024 + h * 64 + dm * 16 + lg * 4] = o;
        }
    }
}

extern "C" void kernel_launch(void* const* d_in, const int* in_sizes, int n_in,
                              void* d_out, int out_size, void* d_ws, size_t ws_size,
                              hipStream_t stream) {
    const float* x  = (const float*)d_in[0];
    const int*   pos = (const int*)d_in[1];
    const float* Wq = (const float*)d_in[2];
    const float* Wk = (const float*)d_in[3];
    const float* Wv = (const float*)d_in[4];
    const float* Wo = (const float*)d_in[5];
    float* out = (float*)d_out;
    char* ws = (char*)d_ws;
    const size_t MB = 1024 * 1024;
    u16* xb   = (u16*)(ws + 0);         //  8 MB  x bf16 (4096x1024)
    u16* wqkv = (u16*)(ws + 8  * MB);   //  6 MB  fused [Wq;Wk;Wv] (3072x1024)
    u16* wob  = (u16*)(ws + 14 * MB);   //  2 MB
    u16* Yqkv = (u16*)(ws + 16 * MB);   // 24 MB  (b,s,3072)
    u16* Qh   = (u16*)(ws + 40 * MB);   //  8 MB  (b,h,s,d') pre-scaled, d-permuted
    u16* Kh   = (u16*)(ws + 48 * MB);   //  8 MB  (b,h,s,d') d-permuted
    u16* Vt   = (u16*)(ws + 56 * MB);   //  8 MB  (b,h,d,s') s-permuted
    u16* Oa   = Yqkv;                   // reuse: Yqkv dead after rope+vtrans

    cvt_kernel<<<4096, 256, 0, stream>>>(x, xb, 1048576);
    // 1024 blocks x 256 thr = 262,144 float4s per weight (FIX: was 256 -> only 1/4 converted)
    cvtw_kernel<<<dim3(1024, 4), 256, 0, stream>>>(Wq, Wk, Wv, Wo,
                                                   wqkv, wqkv + 1024 * 1024, wqkv + 2048 * 1024, wob);

    gemm_bt<<<dim3(24, 32), 256, 0, stream>>>(xb, wqkv, nullptr, Yqkv, 4096, 3072, 1024);

    rope_kernel<<<8192, 256, 0, stream>>>(Yqkv, pos, Qh, Kh);
    vtrans_kernel<<<dim3(32, 32), 256, 0, stream>>>(Yqkv, Vt);

    attn_kernel<<<512, 256, 0, stream>>>(Qh, Kh, Vt, Oa);

    gemm_bt<<<dim3(8, 32), 256, 0, stream>>>(Oa, wob, out, nullptr, 4096, 1024, 1024);
}

// Round 6
// 153.443 us; speedup vs baseline: 3.3167x; 1.0027x over previous
//
#include <hip/hip_runtime.h>
#include <hip/hip_bf16.h>
#include <math.h>

typedef __attribute__((ext_vector_type(4))) float   f32x4;
typedef __attribute__((ext_vector_type(8))) __bf16  bf16x8;
typedef __attribute__((ext_vector_type(8))) unsigned short ushort8;
typedef unsigned short u16;

#define QSCALE 0.1803368801111729f   // 0.125 * log2(e): softmax done in exp2 domain

__device__ __forceinline__ u16 f2b(float f) {
    unsigned u = __builtin_bit_cast(unsigned, f);
    u += 0x7fff + ((u >> 16) & 1);          // RNE
    return (u16)(u >> 16);
}
// async global->LDS, 16B per lane; LDS dest = wave-uniform base + lane*16
__device__ __forceinline__ void gl16(const void* g, void* l) {
    __builtin_amdgcn_global_load_lds((const __attribute__((address_space(1))) void*)g,
                                     (__attribute__((address_space(3))) void*)l, 16, 0, 0);
}
// k-permutation within a 32-elem chunk: dim d stored at pos32(d), so that MFMA frag
// element j (hw k = (j>>2)*16 + lg*4 + (j&3)) is CONTIGUOUS 16B in LDS.
__device__ __forceinline__ int pos32(int d) {
    return ((d & 15) >> 2) * 8 + ((d >> 4) & 1) * 4 + (d & 3);
}
// single ds_read_b128 fragment from a 64-col permuted+swizzled LDS tile
__device__ __forceinline__ bf16x8 frag128(const u16* tile, int row, int half, int lg) {
    int gran = (half * 4 + lg) ^ (row & 7);
    return *(const bf16x8*)(tile + row * 64 + gran * 8);
}

// ---------------- f32 -> bf16 convert ----------------
__global__ void cvt_kernel(const float* __restrict__ src, u16* __restrict__ dst, int n4) {
    int i = blockIdx.x * 256 + threadIdx.x;
    if (i < n4) {
        float4 v = ((const float4*)src)[i];
        ((ushort4*)dst)[i] = make_ushort4(f2b(v.x), f2b(v.y), f2b(v.z), f2b(v.w));
    }
}
__global__ void cvtw_kernel(const float* __restrict__ s0, const float* __restrict__ s1,
                            const float* __restrict__ s2, const float* __restrict__ s3,
                            u16* __restrict__ d0, u16* __restrict__ d1,
                            u16* __restrict__ d2, u16* __restrict__ d3) {
    int i = blockIdx.x * 256 + threadIdx.x;      // [0, 262144) float4s per weight
    int w = blockIdx.y;
    const float* s = (w == 0) ? s0 : (w == 1) ? s1 : (w == 2) ? s2 : s3;
    u16* d        = (w == 0) ? d0 : (w == 1) ? d1 : (w == 2) ? d2 : d3;
    float4 v = ((const float4*)s)[i];
    ((ushort4*)d)[i] = make_ushort4(f2b(v.x), f2b(v.y), f2b(v.z), f2b(v.w));
}

// ---------------- RoPE cos/sin table: csn[s*32+i] = (cos, sin) ----------------
__global__ void csn_kernel(const int* __restrict__ pos, float2* __restrict__ csn) {
    int idx = blockIdx.x * 256 + threadIdx.x;    // 65536
    int s = idx >> 5, i = idx & 31;
    float p = (float)pos[s];
    float ang = p * exp2f((float)i * (-13.28771237954945f / 32.f));
    csn[idx] = make_float2(cosf(ang), sinf(ang));
}

// ---------------- shared GEMM core pieces ----------------
__device__ __forceinline__ bf16x8 ldfG(const u16* tile, int row, int lg) {
    const u16* rp = tile + row * 32;
    const int sw = ((row >> 1) & 3) << 3;
    typedef __attribute__((ext_vector_type(4))) __bf16 bf16x4;
    bf16x4 lo = *(const bf16x4*)(rp + ((lg * 4) ^ sw));
    bf16x4 hi = *(const bf16x4*)(rp + ((16 + lg * 4) ^ sw));
    return __builtin_shufflevector(lo, hi, 0, 1, 2, 3, 4, 5, 6, 7);
}

// ---------------- fused QKV GEMM: Y = x*Wqkv^T with RoPE/relayout epilogue ----------------
// grid (24, 32): bx 0-7 -> Qh (rope+scale), 8-15 -> Kh (rope), 16-23 -> Vt (transpose)
__global__ __launch_bounds__(256) void gemm_qkv(
    const u16* __restrict__ A, const u16* __restrict__ Bw, const float2* __restrict__ csn,
    u16* __restrict__ Qh, u16* __restrict__ Kh, u16* __restrict__ Vt)
{
    __shared__ u16 shm[128 * 132];               // gemm dbuf (16384 u16) / V-transpose (16896 u16)
    const int K = 1024;
    const int tid = threadIdx.x;
    const int lane = tid & 63, wv = tid >> 6;
    const int l15 = lane & 15, lg = lane >> 4;
    const int mblk = blockIdx.y * 128, nblk = blockIdx.x * 128;
    const int m0 = (wv >> 1) * 64, n0 = (wv & 1) * 64;
    const int NIT = K >> 5;

    f32x4 acc[4][4];
    for (int a = 0; a < 4; ++a)
        for (int b = 0; b < 4; ++b)
            for (int r = 0; r < 4; ++r) acc[a][b][r] = 0.f;

#pragma unroll
    for (int r = 0; r < 2; ++r) {
        int c = r * 256 + tid;
        int row = c >> 2;
        int col = ((c & 3) << 3) ^ (((row >> 1) & 3) << 3);
        gl16(A  + (size_t)(mblk + row) * K + col, shm        + (r * 256 + wv * 64) * 8);
        gl16(Bw + (size_t)(nblk + row) * K + col, shm + 8192 + (r * 256 + wv * 64) * 8);
    }
    for (int it = 0; it < NIT; ++it) {
        const int cur = it & 1;
        u16* curA = shm + cur * 4096;
        u16* curB = shm + 8192 + cur * 4096;
        __syncthreads();
        if (it + 1 < NIT) {
            const int kt = (it + 1) << 5;
            u16* nxtA = shm + (cur ^ 1) * 4096;
            u16* nxtB = shm + 8192 + (cur ^ 1) * 4096;
#pragma unroll
            for (int r = 0; r < 2; ++r) {
                int c = r * 256 + tid;
                int row = c >> 2;
                int col = ((c & 3) << 3) ^ (((row >> 1) & 3) << 3);
                gl16(A  + (size_t)(mblk + row) * K + kt + col, nxtA + (r * 256 + wv * 64) * 8);
                gl16(Bw + (size_t)(nblk + row) * K + kt + col, nxtB + (r * 256 + wv * 64) * 8);
            }
        }
        bf16x8 af[4], bfr[4];
#pragma unroll
        for (int mm = 0; mm < 4; ++mm) af[mm] = ldfG(curA, m0 + mm * 16 + l15, lg);
#pragma unroll
        for (int nn = 0; nn < 4; ++nn) bfr[nn] = ldfG(curB, n0 + nn * 16 + l15, lg);
#pragma unroll
        for (int mm = 0; mm < 4; ++mm)
#pragma unroll
            for (int nn = 0; nn < 4; ++nn)
                acc[mm][nn] = __builtin_amdgcn_mfma_f32_16x16x32_bf16(af[mm], bfr[nn], acc[mm][nn], 0, 0, 0);
    }

    const int role = nblk >> 10;                 // 0=Q, 1=K, 2=V
    if (role < 2) {
        // RoPE epilogue: partner value lives in lane^1 (adjacent e)
        u16* dst = role ? Kh : Qh;
        const float scale = role ? 1.f : QSCALE;
#pragma unroll
        for (int mm = 0; mm < 4; ++mm)
#pragma unroll
            for (int nn = 0; nn < 4; ++nn) {
                int colq = (nblk + n0 + nn * 16 + l15) & 1023;
                int h = colq >> 6, dd = colq & 63;
                int outd = (dd & 32) + pos32(dd & 31);
                int odd = dd & 1, i = dd >> 1;
#pragma unroll
                for (int r = 0; r < 4; ++r) {
                    int rowg = mblk + m0 + mm * 16 + lg * 4 + r;
                    int b = rowg >> 11, s = rowg & 2047;
                    float2 cs = csn[s * 32 + i];
                    float v = acc[mm][nn][r];
                    float p = __shfl_xor(v, 1);
                    float o = odd ? (p * cs.y + v * cs.x) : (v * cs.x - p * cs.y);
                    dst[((size_t)(b * 16 + h) * 2048 + s) * 64 + outd] = f2b(o * scale);
                }
            }
    } else {
        // V transpose epilogue via LDS
        __syncthreads();                         // all waves done reading gemm bufs
#pragma unroll
        for (int mm = 0; mm < 4; ++mm)
#pragma unroll
            for (int nn = 0; nn < 4; ++nn)
#pragma unroll
                for (int r = 0; r < 4; ++r)
                    shm[(m0 + mm * 16 + lg * 4 + r) * 132 + n0 + nn * 16 + l15] = f2b(acc[mm][nn][r]);
        __syncthreads();
        const int el = tid >> 1, half = tid & 1;
        const int colg = nblk - 2048 + el;
        const int h = colg >> 6, dd = colg & 63;
        const int b = mblk >> 11;
        const int sbase = (mblk & 2047) + half * 64;
        u16 vals[64];
#pragma unroll
        for (int o = 0; o < 64; ++o) {
            int oo = o & 31;
            int d = (o & 32) + ((oo >> 2) & 1) * 16 + (oo >> 3) * 4 + (oo & 3);
            vals[o] = shm[(half * 64 + d) * 132 + el];
        }
        u16* dst = Vt + ((size_t)(b * 16 + h) * 64 + dd) * 2048 + sbase;
#pragma unroll
        for (int a = 0; a < 8; ++a)
            *(ushort8*)(dst + a * 8) = *(const ushort8*)(vals + a * 8);
    }
}

// ---------------- plain GEMM (out-proj): C[M,N] = A[M,K] * Bw[N,K]^T -> f32 ----------------
__global__ __launch_bounds__(256) void gemm_bt(
    const u16* __restrict__ A, const u16* __restrict__ Bw,
    float* __restrict__ Cf, int M, int N, int K)
{
    __shared__ u16 lsA[2][128 * 32];
    __shared__ u16 lsB[2][128 * 32];
    const int tid = threadIdx.x;
    const int lane = tid & 63, wv = tid >> 6;
    const int l15 = lane & 15, lg = lane >> 4;
    const int mblk = blockIdx.y * 128, nblk = blockIdx.x * 128;
    const int m0 = (wv >> 1) * 64, n0 = (wv & 1) * 64;
    const int NIT = K >> 5;

    f32x4 acc[4][4];
    for (int a = 0; a < 4; ++a)
        for (int b = 0; b < 4; ++b)
            for (int r = 0; r < 4; ++r) acc[a][b][r] = 0.f;

#pragma unroll
    for (int r = 0; r < 2; ++r) {
        int c = r * 256 + tid;
        int row = c >> 2;
        int col = ((c & 3) << 3) ^ (((row >> 1) & 3) << 3);
        gl16(A  + (size_t)(mblk + row) * K + col, &lsA[0][(r * 256 + wv * 64) * 8]);
        gl16(Bw + (size_t)(nblk + row) * K + col, &lsB[0][(r * 256 + wv * 64) * 8]);
    }
    for (int it = 0; it < NIT; ++it) {
        const int cur = it & 1;
        __syncthreads();
        if (it + 1 < NIT) {
            const int kt = (it + 1) << 5;
#pragma unroll
            for (int r = 0; r < 2; ++r) {
                int c = r * 256 + tid;
                int row = c >> 2;
                int col = ((c & 3) << 3) ^ (((row >> 1) & 3) << 3);
                gl16(A  + (size_t)(mblk + row) * K + kt + col, &lsA[cur ^ 1][(r * 256 + wv * 64) * 8]);
                gl16(Bw + (size_t)(nblk + row) * K + kt + col, &lsB[cur ^ 1][(r * 256 + wv * 64) * 8]);
            }
        }
        bf16x8 af[4], bfr[4];
#pragma unroll
        for (int mm = 0; mm < 4; ++mm) af[mm] = ldfG(lsA[cur], m0 + mm * 16 + l15, lg);
#pragma unroll
        for (int nn = 0; nn < 4; ++nn) bfr[nn] = ldfG(lsB[cur], n0 + nn * 16 + l15, lg);
#pragma unroll
        for (int mm = 0; mm < 4; ++mm)
#pragma unroll
            for (int nn = 0; nn < 4; ++nn)
                acc[mm][nn] = __builtin_amdgcn_mfma_f32_16x16x32_bf16(af[mm], bfr[nn], acc[mm][nn], 0, 0, 0);
    }
#pragma unroll
    for (int mm = 0; mm < 4; ++mm)
#pragma unroll
        for (int nn = 0; nn < 4; ++nn)
#pragma unroll
            for (int r = 0; r < 4; ++r) {
                int row = mblk + m0 + mm * 16 + lg * 4 + r;
                int col = nblk + n0 + nn * 16 + l15;
                Cf[(size_t)row * N + col] = acc[mm][nn][r];
            }
}

// ---------------- Flash attention: QBLK=128, KVBLK=64, dbuf, causal-split, defer-max ----------------
__device__ __forceinline__ void stage_kv(const u16* Kp, const u16* Vp, int kt,
                                         u16* bK, u16* bV, int tid, int wv) {
#pragma unroll
    for (int r = 0; r < 2; ++r) {
        int c = r * 256 + tid;
        int row = c >> 3;
        int col = ((c & 7) ^ (row & 7)) * 8;
        gl16(Kp + (size_t)(kt * 64 + row) * 64 + col, bK + (r * 256 + wv * 64) * 8);
        gl16(Vp + (size_t)row * 2048 + kt * 64 + col, bV + (r * 256 + wv * 64) * 8);
    }
}
__global__ __launch_bounds__(256) void attn_kernel(
    const u16* __restrict__ Qh, const u16* __restrict__ Kh, const u16* __restrict__ Vt,
    u16* __restrict__ Oa)
{
    __shared__ u16 lsQ[128 * 64];
    __shared__ u16 lsK[2][64 * 64];
    __shared__ u16 lsV[2][64 * 64];
    const int tid = threadIdx.x;
    const int lane = tid & 63, wv = tid >> 6;
    const int l15 = lane & 15, lg = lane >> 4;
    const int id = blockIdx.x;
    const int gq = id >> 5;
    const int qt = (id < 256) ? (15 - gq) : (gq - 8);
    const int bh = id & 31;
    const int b = bh >> 4, h = bh & 15;
    const u16* Qp = Qh + (size_t)bh * 2048 * 64;
    const u16* Kp = Kh + (size_t)bh * 2048 * 64;
    const u16* Vp = Vt + (size_t)bh * 64 * 2048;

#pragma unroll
    for (int r = 0; r < 4; ++r) {
        int c = r * 256 + tid;
        int row = c >> 3;
        int col = ((c & 7) ^ (row & 7)) * 8;
        gl16(Qp + (size_t)(qt * 128 + row) * 64 + col, &lsQ[(r * 256 + wv * 64) * 8]);
    }
    stage_kv(Kp, Vp, 0, lsK[0], lsV[0], tid, wv);
    __syncthreads();

    bf16x8 qf[2][2];
#pragma unroll
    for (int m = 0; m < 2; ++m)
#pragma unroll
        for (int ds = 0; ds < 2; ++ds)
            qf[m][ds] = frag128(lsQ, wv * 32 + m * 16 + l15, ds, lg);

    f32x4 accO[2][4];
#pragma unroll
    for (int m = 0; m < 2; ++m)
        for (int dm = 0; dm < 4; ++dm)
            for (int r = 0; r < 4; ++r) accO[m][dm][r] = 0.f;
    float mrun[2] = { -3e38f, -3e38f }, lrun[2] = { 0.f, 0.f };
    const int nfull = 2 * qt + (wv >> 1);
    const int NT = 2 * qt + 2;

    for (int kt = 0; kt < NT; ++kt) {
        const int cur = kt & 1;
        if (kt + 1 < NT)
            stage_kv(Kp, Vp, kt + 1, lsK[cur ^ 1], lsV[cur ^ 1], tid, wv);
        if (kt <= nfull) {
            f32x4 sa[2][4];
            __builtin_amdgcn_s_setprio(1);
#pragma unroll
            for (int kb = 0; kb < 4; ++kb) {
                int krow = kb * 16 + l15;
                bf16x8 kf0 = frag128(lsK[cur], krow, 0, lg);
                bf16x8 kf1 = frag128(lsK[cur], krow, 1, lg);
#pragma unroll
                for (int m = 0; m < 2; ++m) {
                    f32x4 s = { 0.f, 0.f, 0.f, 0.f };
                    s = __builtin_amdgcn_mfma_f32_16x16x32_bf16(kf0, qf[m][0], s, 0, 0, 0);
                    s = __builtin_amdgcn_mfma_f32_16x16x32_bf16(kf1, qf[m][1], s, 0, 0, 0);
                    sa[m][kb] = s;
                }
            }
            __builtin_amdgcn_s_setprio(0);
            if (kt == nfull) {
#pragma unroll
                for (int m = 0; m < 2; ++m) {
                    int qg = qt * 128 + wv * 32 + m * 16 + l15;
#pragma unroll
                    for (int kb = 0; kb < 4; ++kb)
#pragma unroll
                        for (int r = 0; r < 4; ++r)
                            if (kt * 64 + kb * 16 + lg * 4 + r > qg) sa[m][kb][r] = -1e30f;
                }
            }
            float pm[2];
#pragma unroll
            for (int m = 0; m < 2; ++m) {
                float a = fmaxf(fmaxf(sa[m][0][0], sa[m][0][1]), fmaxf(sa[m][0][2], sa[m][0][3]));
                float c = fmaxf(fmaxf(sa[m][1][0], sa[m][1][1]), fmaxf(sa[m][1][2], sa[m][1][3]));
                float d = fmaxf(fmaxf(sa[m][2][0], sa[m][2][1]), fmaxf(sa[m][2][2], sa[m][2][3]));
                float e = fmaxf(fmaxf(sa[m][3][0], sa[m][3][1]), fmaxf(sa[m][3][2], sa[m][3][3]));
                float x = fmaxf(fmaxf(a, c), fmaxf(d, e));
                x = fmaxf(x, __shfl_xor(x, 16));
                x = fmaxf(x, __shfl_xor(x, 32));
                pm[m] = x;
            }
            bool near = (pm[0] <= mrun[0] + 8.f) && (pm[1] <= mrun[1] + 8.f);
            if (!__all(near)) {
#pragma unroll
                for (int m = 0; m < 2; ++m) {
                    float mnew = fmaxf(mrun[m], pm[m]);
                    float fac = exp2f(mrun[m] - mnew);
                    lrun[m] *= fac;
#pragma unroll
                    for (int dm = 0; dm < 4; ++dm)
#pragma unroll
                        for (int r = 0; r < 4; ++r) accO[m][dm][r] *= fac;
                    mrun[m] = mnew;
                }
            }
            float ps[2] = { 0.f, 0.f };
#pragma unroll
            for (int m = 0; m < 2; ++m)
#pragma unroll
                for (int kb = 0; kb < 4; ++kb)
#pragma unroll
                    for (int r = 0; r < 4; ++r) {
                        float pe = exp2f(sa[m][kb][r] - mrun[m]);
                        sa[m][kb][r] = pe;
                        ps[m] += pe;
                    }
#pragma unroll
            for (int m = 0; m < 2; ++m) {
                float x = ps[m];
                x += __shfl_xor(x, 16);
                x += __shfl_xor(x, 32);
                lrun[m] += x;
            }
            bf16x8 pf[2][2];
#pragma unroll
            for (int m = 0; m < 2; ++m)
#pragma unroll
                for (int ks = 0; ks < 2; ++ks) {
                    bf16x8 t;
#pragma unroll
                    for (int j = 0; j < 4; ++j) {
                        t[j]     = (__bf16)sa[m][2 * ks][j];
                        t[4 + j] = (__bf16)sa[m][2 * ks + 1][j];
                    }
                    pf[m][ks] = t;
                }
            __builtin_amdgcn_s_setprio(1);
#pragma unroll
            for (int dm = 0; dm < 4; ++dm) {
                int vrow = dm * 16 + l15;
#pragma unroll
                for (int ks = 0; ks < 2; ++ks) {
                    bf16x8 vf = frag128(lsV[cur], vrow, ks, lg);
#pragma unroll
                    for (int m = 0; m < 2; ++m)
                        accO[m][dm] = __builtin_amdgcn_mfma_f32_16x16x32_bf16(vf, pf[m][ks], accO[m][dm], 0, 0, 0);
                }
            }
            __builtin_amdgcn_s_setprio(0);
        }
        __syncthreads();
    }
#pragma unroll
    for (int m = 0; m < 2; ++m) {
        float inv = 1.f / lrun[m];
        int srow = qt * 128 + wv * 32 + m * 16 + l15;
#pragma unroll
        for (int dm = 0; dm < 4; ++dm) {
            ushort4 o = make_ushort4(f2b(accO[m][dm][0] * inv), f2b(accO[m][dm][1] * inv),
                                     f2b(accO[m][dm][2] * inv), f2b(accO[m][dm][3] * inv));
            *(ushort4*)&Oa[((size_t)b * 2048 + srow) * 1024 + h * 64 + dm * 16 + lg * 4] = o;
        }
    }
}

extern "C" void kernel_launch(void* const* d_in, const int* in_sizes, int n_in,
                              void* d_out, int out_size, void* d_ws, size_t ws_size,
                              hipStream_t stream) {
    const float* x  = (const float*)d_in[0];
    const int*   pos = (const int*)d_in[1];
    const float* Wq = (const float*)d_in[2];
    const float* Wk = (const float*)d_in[3];
    const float* Wv = (const float*)d_in[4];
    const float* Wo = (const float*)d_in[5];
    float* out = (float*)d_out;
    char* ws = (char*)d_ws;
    const size_t MB = 1024 * 1024;
    u16*    xb   = (u16*)   (ws + 0);        //  8 MB  x bf16 (4096x1024)
    u16*    wqkv = (u16*)   (ws + 8  * MB);  //  6 MB  fused [Wq;Wk;Wv] (3072x1024)
    u16*    wob  = (u16*)   (ws + 14 * MB);  //  2 MB
    float2* csn  = (float2*)(ws + 16 * MB);  //  0.5 MB cos/sin table (2048x32)
    u16*    Qh   = (u16*)   (ws + 24 * MB);  //  8 MB  (b,h,s,d') pre-scaled, d-permuted
    u16*    Kh   = (u16*)   (ws + 32 * MB);  //  8 MB  (b,h,s,d') d-permuted
    u16*    Vt   = (u16*)   (ws + 40 * MB);  //  8 MB  (b,h,d,s') s-permuted
    u16*    Oa   = (u16*)   (ws + 48 * MB);  //  8 MB  attn out (b,s,e) bf16

    cvt_kernel<<<4096, 256, 0, stream>>>(x, xb, 1048576);
    cvtw_kernel<<<dim3(1024, 4), 256, 0, stream>>>(Wq, Wk, Wv, Wo,
                                                   wqkv, wqkv + 1024 * 1024, wqkv + 2048 * 1024, wob);
    csn_kernel<<<256, 256, 0, stream>>>(pos, csn);

    // fused QKV projection + RoPE + relayout
    gemm_qkv<<<dim3(24, 32), 256, 0, stream>>>(xb, wqkv, csn, Qh, Kh, Vt);

    attn_kernel<<<512, 256, 0, stream>>>(Qh, Kh, Vt, Oa);

    gemm_bt<<<dim3(8, 32), 256, 0, stream>>>(Oa, wob, out, 4096, 1024, 1024);
}

// Round 7
// 133.190 us; speedup vs baseline: 3.8211x; 1.1521x over previous
//
#include <hip/hip_runtime.h>
#include <hip/hip_bf16.h>
#include <math.h>

typedef __attribute__((ext_vector_type(4))) float   f32x4;
typedef __attribute__((ext_vector_type(8))) __bf16  bf16x8;
typedef __attribute__((ext_vector_type(8))) unsigned short ushort8;
typedef unsigned short u16;

#define QSCALE 0.1803368801111729f   // 0.125 * log2(e): softmax done in exp2 domain

__device__ __forceinline__ u16 f2b(float f) {
    unsigned u = __builtin_bit_cast(unsigned, f);
    u += 0x7fff + ((u >> 16) & 1);          // RNE
    return (u16)(u >> 16);
}
// async global->LDS, 16B per lane; LDS dest = wave-uniform base + lane*16
__device__ __forceinline__ void gl16(const void* g, void* l) {
    __builtin_amdgcn_global_load_lds((const __attribute__((address_space(1))) void*)g,
                                     (__attribute__((address_space(3))) void*)l, 16, 0, 0);
}
// k-permutation within a 32-elem chunk: dim d stored at pos32(d), so that MFMA frag
// element j (hw k = (j>>2)*16 + lg*4 + (j&3)) is CONTIGUOUS 16B in LDS.
__device__ __forceinline__ int pos32(int d) {
    return ((d & 15) >> 2) * 8 + ((d >> 4) & 1) * 4 + (d & 3);
}
// single ds_read_b128 fragment from a 64-col permuted+swizzled LDS tile
__device__ __forceinline__ bf16x8 frag128(const u16* tile, int row, int half, int lg) {
    int gran = (half * 4 + lg) ^ (row & 7);
    return *(const bf16x8*)(tile + row * 64 + gran * 8);
}

// ---------------- fused prep: x/weights f32->bf16 + cos/sin table ----------------
// blocks [0,4096): x ; [4096,8192): 4 weights ; [8192,8448): csn
__global__ void prep_kernel(const float* __restrict__ x,
                            const float* __restrict__ Wq, const float* __restrict__ Wk,
                            const float* __restrict__ Wv, const float* __restrict__ Wo,
                            const int* __restrict__ pos,
                            u16* __restrict__ xb, u16* __restrict__ wqkv, u16* __restrict__ wob,
                            float2* __restrict__ csn)
{
    int bx = blockIdx.x, tid = threadIdx.x;
    if (bx < 4096) {
        int i = bx * 256 + tid;
        float4 v = ((const float4*)x)[i];
        ((ushort4*)xb)[i] = make_ushort4(f2b(v.x), f2b(v.y), f2b(v.z), f2b(v.w));
    } else if (bx < 8192) {
        int j = bx - 4096;
        int w = j >> 10;
        int i = (j & 1023) * 256 + tid;
        const float* s = (w == 0) ? Wq : (w == 1) ? Wk : (w == 2) ? Wv : Wo;
        u16* d = (w == 3) ? wob : (wqkv + (size_t)w * 1048576);
        float4 v = ((const float4*)s)[i];
        ((ushort4*)d)[i] = make_ushort4(f2b(v.x), f2b(v.y), f2b(v.z), f2b(v.w));
    } else {
        int idx = (bx - 8192) * 256 + tid;       // [0, 65536)
        int s = idx >> 5, i = idx & 31;
        float p = (float)pos[s];
        float ang = p * exp2f((float)i * (-13.28771237954945f / 32.f));
        csn[idx] = make_float2(cosf(ang), sinf(ang));
    }
}

// ---------------- shared GEMM core pieces ----------------
__device__ __forceinline__ bf16x8 ldfG(const u16* tile, int row, int lg) {
    const u16* rp = tile + row * 32;
    const int sw = ((row >> 1) & 3) << 3;
    typedef __attribute__((ext_vector_type(4))) __bf16 bf16x4;
    bf16x4 lo = *(const bf16x4*)(rp + ((lg * 4) ^ sw));
    bf16x4 hi = *(const bf16x4*)(rp + ((16 + lg * 4) ^ sw));
    return __builtin_shufflevector(lo, hi, 0, 1, 2, 3, 4, 5, 6, 7);
}

// ---------------- fused QKV GEMM: Y = x*Wqkv^T with RoPE/relayout epilogue ----------------
// grid (24, 32): bx 0-7 -> Qh (rope+scale), 8-15 -> Kh (rope), 16-23 -> Vt (transpose)
__global__ __launch_bounds__(256) void gemm_qkv(
    const u16* __restrict__ A, const u16* __restrict__ Bw, const float2* __restrict__ csn,
    u16* __restrict__ Qh, u16* __restrict__ Kh, u16* __restrict__ Vt)
{
    __shared__ u16 shm[128 * 132];               // gemm dbuf (16384 u16) / V-transpose (16896 u16)
    const int K = 1024;
    const int tid = threadIdx.x;
    const int lane = tid & 63, wv = tid >> 6;
    const int l15 = lane & 15, lg = lane >> 4;
    const int mblk = blockIdx.y * 128, nblk = blockIdx.x * 128;
    const int m0 = (wv >> 1) * 64, n0 = (wv & 1) * 64;
    const int NIT = K >> 5;

    f32x4 acc[4][4];
    for (int a = 0; a < 4; ++a)
        for (int b = 0; b < 4; ++b)
            for (int r = 0; r < 4; ++r) acc[a][b][r] = 0.f;

#pragma unroll
    for (int r = 0; r < 2; ++r) {
        int c = r * 256 + tid;
        int row = c >> 2;
        int col = ((c & 3) << 3) ^ (((row >> 1) & 3) << 3);
        gl16(A  + (size_t)(mblk + row) * K + col, shm        + (r * 256 + wv * 64) * 8);
        gl16(Bw + (size_t)(nblk + row) * K + col, shm + 8192 + (r * 256 + wv * 64) * 8);
    }
    for (int it = 0; it < NIT; ++it) {
        const int cur = it & 1;
        u16* curA = shm + cur * 4096;
        u16* curB = shm + 8192 + cur * 4096;
        __syncthreads();
        if (it + 1 < NIT) {
            const int kt = (it + 1) << 5;
            u16* nxtA = shm + (cur ^ 1) * 4096;
            u16* nxtB = shm + 8192 + (cur ^ 1) * 4096;
#pragma unroll
            for (int r = 0; r < 2; ++r) {
                int c = r * 256 + tid;
                int row = c >> 2;
                int col = ((c & 3) << 3) ^ (((row >> 1) & 3) << 3);
                gl16(A  + (size_t)(mblk + row) * K + kt + col, nxtA + (r * 256 + wv * 64) * 8);
                gl16(Bw + (size_t)(nblk + row) * K + kt + col, nxtB + (r * 256 + wv * 64) * 8);
            }
        }
        bf16x8 af[4], bfr[4];
#pragma unroll
        for (int mm = 0; mm < 4; ++mm) af[mm] = ldfG(curA, m0 + mm * 16 + l15, lg);
#pragma unroll
        for (int nn = 0; nn < 4; ++nn) bfr[nn] = ldfG(curB, n0 + nn * 16 + l15, lg);
#pragma unroll
        for (int mm = 0; mm < 4; ++mm)
#pragma unroll
            for (int nn = 0; nn < 4; ++nn)
                acc[mm][nn] = __builtin_amdgcn_mfma_f32_16x16x32_bf16(af[mm], bfr[nn], acc[mm][nn], 0, 0, 0);
    }

    const int role = nblk >> 10;                 // 0=Q, 1=K, 2=V
    if (role < 2) {
        // RoPE epilogue: partner value lives in lane^1 (adjacent e)
        u16* dst = role ? Kh : Qh;
        const float scale = role ? 1.f : QSCALE;
#pragma unroll
        for (int mm = 0; mm < 4; ++mm)
#pragma unroll
            for (int nn = 0; nn < 4; ++nn) {
                int colq = (nblk + n0 + nn * 16 + l15) & 1023;
                int h = colq >> 6, dd = colq & 63;
                int outd = (dd & 32) + pos32(dd & 31);
                int odd = dd & 1, i = dd >> 1;
#pragma unroll
                for (int r = 0; r < 4; ++r) {
                    int rowg = mblk + m0 + mm * 16 + lg * 4 + r;
                    int b = rowg >> 11, s = rowg & 2047;
                    float2 cs = csn[s * 32 + i];
                    float v = acc[mm][nn][r];
                    float p = __shfl_xor(v, 1);
                    float o = odd ? (p * cs.y + v * cs.x) : (v * cs.x - p * cs.y);
                    dst[((size_t)(b * 16 + h) * 2048 + s) * 64 + outd] = f2b(o * scale);
                }
            }
    } else {
        // V transpose epilogue via LDS
        __syncthreads();                         // all waves done reading gemm bufs
#pragma unroll
        for (int mm = 0; mm < 4; ++mm)
#pragma unroll
            for (int nn = 0; nn < 4; ++nn)
#pragma unroll
                for (int r = 0; r < 4; ++r)
                    shm[(m0 + mm * 16 + lg * 4 + r) * 132 + n0 + nn * 16 + l15] = f2b(acc[mm][nn][r]);
        __syncthreads();
        const int el = tid >> 1, half = tid & 1;
        const int colg = nblk - 2048 + el;
        const int h = colg >> 6, dd = colg & 63;
        const int b = mblk >> 11;
        const int sbase = (mblk & 2047) + half * 64;
        u16 vals[64];
#pragma unroll
        for (int o = 0; o < 64; ++o) {
            int oo = o & 31;
            int d = (o & 32) + ((oo >> 2) & 1) * 16 + (oo >> 3) * 4 + (oo & 3);
            vals[o] = shm[(half * 64 + d) * 132 + el];
        }
        u16* dst = Vt + ((size_t)(b * 16 + h) * 64 + dd) * 2048 + sbase;
#pragma unroll
        for (int a = 0; a < 8; ++a)
            *(ushort8*)(dst + a * 8) = *(const ushort8*)(vals + a * 8);
    }
}

// ---------------- plain GEMM (out-proj): C[M,N] = A[M,K] * Bw[N,K]^T -> f32 ----------------
__global__ __launch_bounds__(256) void gemm_bt(
    const u16* __restrict__ A, const u16* __restrict__ Bw,
    float* __restrict__ Cf, int M, int N, int K)
{
    __shared__ u16 lsA[2][128 * 32];
    __shared__ u16 lsB[2][128 * 32];
    const int tid = threadIdx.x;
    const int lane = tid & 63, wv = tid >> 6;
    const int l15 = lane & 15, lg = lane >> 4;
    const int mblk = blockIdx.y * 128, nblk = blockIdx.x * 128;
    const int m0 = (wv >> 1) * 64, n0 = (wv & 1) * 64;
    const int NIT = K >> 5;

    f32x4 acc[4][4];
    for (int a = 0; a < 4; ++a)
        for (int b = 0; b < 4; ++b)
            for (int r = 0; r < 4; ++r) acc[a][b][r] = 0.f;

#pragma unroll
    for (int r = 0; r < 2; ++r) {
        int c = r * 256 + tid;
        int row = c >> 2;
        int col = ((c & 3) << 3) ^ (((row >> 1) & 3) << 3);
        gl16(A  + (size_t)(mblk + row) * K + col, &lsA[0][(r * 256 + wv * 64) * 8]);
        gl16(Bw + (size_t)(nblk + row) * K + col, &lsB[0][(r * 256 + wv * 64) * 8]);
    }
    for (int it = 0; it < NIT; ++it) {
        const int cur = it & 1;
        __syncthreads();
        if (it + 1 < NIT) {
            const int kt = (it + 1) << 5;
#pragma unroll
            for (int r = 0; r < 2; ++r) {
                int c = r * 256 + tid;
                int row = c >> 2;
                int col = ((c & 3) << 3) ^ (((row >> 1) & 3) << 3);
                gl16(A  + (size_t)(mblk + row) * K + kt + col, &lsA[cur ^ 1][(r * 256 + wv * 64) * 8]);
                gl16(Bw + (size_t)(nblk + row) * K + kt + col, &lsB[cur ^ 1][(r * 256 + wv * 64) * 8]);
            }
        }
        bf16x8 af[4], bfr[4];
#pragma unroll
        for (int mm = 0; mm < 4; ++mm) af[mm] = ldfG(lsA[cur], m0 + mm * 16 + l15, lg);
#pragma unroll
        for (int nn = 0; nn < 4; ++nn) bfr[nn] = ldfG(lsB[cur], n0 + nn * 16 + l15, lg);
#pragma unroll
        for (int mm = 0; mm < 4; ++mm)
#pragma unroll
            for (int nn = 0; nn < 4; ++nn)
                acc[mm][nn] = __builtin_amdgcn_mfma_f32_16x16x32_bf16(af[mm], bfr[nn], acc[mm][nn], 0, 0, 0);
    }
#pragma unroll
    for (int mm = 0; mm < 4; ++mm)
#pragma unroll
        for (int nn = 0; nn < 4; ++nn)
#pragma unroll
            for (int r = 0; r < 4; ++r) {
                int row = mblk + m0 + mm * 16 + lg * 4 + r;
                int col = nblk + n0 + nn * 16 + l15;
                Cf[(size_t)row * N + col] = acc[mm][nn][r];
            }
}

// ---------------- Flash attention: 8 waves, QBLK=128, KVBLK=128, dbuf, causal-split ----------------
// shm layout (u16): K dbuf [0,16384) (two 128x64 tiles), V dbuf [16384,32768).
// Q staged transiently at [0,8192) before the KV loop starts.
__device__ __forceinline__ void stage_kv128(const u16* Kp, const u16* Vp, int t,
                                            u16* bK, u16* bV, int tid, int wv) {
#pragma unroll
    for (int r = 0; r < 2; ++r) {
        int c = r * 512 + tid;
        int krow = c >> 3;                       // key-local 0..127
        int kcol = ((c & 7) ^ (krow & 7)) * 8;
        gl16(Kp + (size_t)(t * 128 + krow) * 64 + kcol, bK + (r * 512 + wv * 64) * 8);
        int d = krow & 63, ss = krow >> 6;       // V: rows d, subtile ss
        int vcol = ((c & 7) ^ (d & 7)) * 8;
        gl16(Vp + (size_t)d * 2048 + t * 128 + ss * 64 + vcol, bV + (r * 512 + wv * 64) * 8);
    }
}
__global__ __launch_bounds__(512) void attn_kernel(
    const u16* __restrict__ Qh, const u16* __restrict__ Kh, const u16* __restrict__ Vt,
    u16* __restrict__ Oa)
{
    __shared__ u16 shm[32768];                   // 64 KB
    const int tid = threadIdx.x;
    const int lane = tid & 63, wv = tid >> 6;    // wv 0..7
    const int l15 = lane & 15, lg = lane >> 4;
    const int id = blockIdx.x;
    const int gq = id >> 5;
    const int qt = (id < 256) ? (15 - gq) : (gq - 8);   // heavy+light pairing
    const int bh = id & 31;
    const int b = bh >> 4, h = bh & 15;
    const u16* Qp = Qh + (size_t)bh * 2048 * 64;
    const u16* Kp = Kh + (size_t)bh * 2048 * 64;
    const u16* Vp = Vt + (size_t)bh * 64 * 2048;

    // stage Q (128x64) into shm[0,8192)
#pragma unroll
    for (int r = 0; r < 2; ++r) {
        int c = r * 512 + tid;
        int row = c >> 3;
        int col = ((c & 7) ^ (row & 7)) * 8;
        gl16(Qp + (size_t)(qt * 128 + row) * 64 + col, shm + (r * 512 + wv * 64) * 8);
    }
    __syncthreads();
    bf16x8 qf[2];                                // wave's 16 q-rows
#pragma unroll
    for (int ds = 0; ds < 2; ++ds)
        qf[ds] = frag128(shm, wv * 16 + l15, ds, lg);
    __syncthreads();                             // everyone done reading Q

    stage_kv128(Kp, Vp, 0, shm, shm + 16384, tid, wv);
    __syncthreads();                             // KV tile 0 ready

    f32x4 accO[4];
#pragma unroll
    for (int dm = 0; dm < 4; ++dm)
        for (int r = 0; r < 4; ++r) accO[dm][r] = 0.f;
    float mrun = -3e38f, lrun = 0.f;
    const int st_b = 2 * qt + (wv >> 2);         // boundary 64-key subtile for this wave
    const int NT = qt + 1;                       // 128-key tiles

    for (int t = 0; t < NT; ++t) {
        const int cur = t & 1;
        if (t + 1 < NT)
            stage_kv128(Kp, Vp, t + 1, shm + (cur ^ 1) * 8192, shm + 16384 + (cur ^ 1) * 8192, tid, wv);
        const u16* Kt = shm + cur * 8192;
        const u16* Vb = shm + 16384 + cur * 8192;
#pragma unroll
        for (int ss = 0; ss < 2; ++ss) {
            const int st = 2 * t + ss;
            if (st <= st_b) {
                f32x4 sa[4];
                __builtin_amdgcn_s_setprio(1);
#pragma unroll
                for (int kb = 0; kb < 4; ++kb) {
                    int krow = ss * 64 + kb * 16 + l15;
                    bf16x8 kf0 = frag128(Kt, krow, 0, lg);
                    bf16x8 kf1 = frag128(Kt, krow, 1, lg);
                    f32x4 s = { 0.f, 0.f, 0.f, 0.f };
                    s = __builtin_amdgcn_mfma_f32_16x16x32_bf16(kf0, qf[0], s, 0, 0, 0);
                    s = __builtin_amdgcn_mfma_f32_16x16x32_bf16(kf1, qf[1], s, 0, 0, 0);
                    sa[kb] = s;
                }
                __builtin_amdgcn_s_setprio(0);
                if (st == st_b) {                // boundary subtile: causal mask
                    int qg = qt * 128 + wv * 16 + l15;
#pragma unroll
                    for (int kb = 0; kb < 4; ++kb)
#pragma unroll
                        for (int r = 0; r < 4; ++r)
                            if (st * 64 + kb * 16 + lg * 4 + r > qg) sa[kb][r] = -1e30f;
                }
                float a0 = fmaxf(fmaxf(sa[0][0], sa[0][1]), fmaxf(sa[0][2], sa[0][3]));
                float a1 = fmaxf(fmaxf(sa[1][0], sa[1][1]), fmaxf(sa[1][2], sa[1][3]));
                float a2 = fmaxf(fmaxf(sa[2][0], sa[2][1]), fmaxf(sa[2][2], sa[2][3]));
                float a3 = fmaxf(fmaxf(sa[3][0], sa[3][1]), fmaxf(sa[3][2], sa[3][3]));
                float pm = fmaxf(fmaxf(a0, a1), fmaxf(a2, a3));
                pm = fmaxf(pm, __shfl_xor(pm, 16));
                pm = fmaxf(pm, __shfl_xor(pm, 32));
                // T13 defer-max
                if (!__all(pm <= mrun + 8.f)) {
                    float mnew = fmaxf(mrun, pm);
                    float fac = exp2f(mrun - mnew);
                    lrun *= fac;
#pragma unroll
                    for (int dm = 0; dm < 4; ++dm)
#pragma unroll
                        for (int r = 0; r < 4; ++r) accO[dm][r] *= fac;
                    mrun = mnew;
                }
                float ps = 0.f;
#pragma unroll
                for (int kb = 0; kb < 4; ++kb)
#pragma unroll
                    for (int r = 0; r < 4; ++r) {
                        float pe = exp2f(sa[kb][r] - mrun);
                        sa[kb][r] = pe;
                        ps += pe;
                    }
                ps += __shfl_xor(ps, 16);
                ps += __shfl_xor(ps, 32);
                lrun += ps;
                bf16x8 pf[2];
#pragma unroll
                for (int ks = 0; ks < 2; ++ks) {
                    bf16x8 tt;
#pragma unroll
                    for (int j = 0; j < 4; ++j) {
                        tt[j]     = (__bf16)sa[2 * ks][j];
                        tt[4 + j] = (__bf16)sa[2 * ks + 1][j];
                    }
                    pf[ks] = tt;
                }
                __builtin_amdgcn_s_setprio(1);
#pragma unroll
                for (int dm = 0; dm < 4; ++dm) {
                    int vrow = ss * 64 + dm * 16 + l15;
#pragma unroll
                    for (int ks = 0; ks < 2; ++ks) {
                        bf16x8 vf = frag128(Vb, vrow, ks, lg);
                        accO[dm] = __builtin_amdgcn_mfma_f32_16x16x32_bf16(vf, pf[ks], accO[dm], 0, 0, 0);
                    }
                }
                __builtin_amdgcn_s_setprio(0);
            }
        }
        __syncthreads();                         // next tile staged + this tile's reads done
    }
    float inv = 1.f / lrun;
    int srow = qt * 128 + wv * 16 + l15;
#pragma unroll
    for (int dm = 0; dm < 4; ++dm) {
        ushort4 o = make_ushort4(f2b(accO[dm][0] * inv), f2b(accO[dm][1] * inv),
                                 f2b(accO[dm][2] * inv), f2b(accO[dm][3] * inv));
        *(ushort4*)&Oa[((size_t)b * 2048 + srow) * 1024 + h * 64 + dm * 16 + lg * 4] = o;
    }
}

extern "C" void kernel_launch(void* const* d_in, const int* in_sizes, int n_in,
                              void* d_out, int out_size, void* d_ws, size_t ws_size,
                              hipStream_t stream) {
    const float* x  = (const float*)d_in[0];
    const int*   pos = (const int*)d_in[1];
    const float* Wq = (const float*)d_in[2];
    const float* Wk = (const float*)d_in[3];
    const float* Wv = (const float*)d_in[4];
    const float* Wo = (const float*)d_in[5];
    float* out = (float*)d_out;
    char* ws = (char*)d_ws;
    const size_t MB = 1024 * 1024;
    u16*    xb   = (u16*)   (ws + 0);        //  8 MB  x bf16 (4096x1024)
    u16*    wqkv = (u16*)   (ws + 8  * MB);  //  6 MB  fused [Wq;Wk;Wv] (3072x1024)
    u16*    wob  = (u16*)   (ws + 14 * MB);  //  2 MB
    float2* csn  = (float2*)(ws + 16 * MB);  //  0.5 MB cos/sin table (2048x32)
    u16*    Qh   = (u16*)   (ws + 24 * MB);  //  8 MB  (b,h,s,d') pre-scaled, d-permuted
    u16*    Kh   = (u16*)   (ws + 32 * MB);  //  8 MB  (b,h,s,d') d-permuted
    u16*    Vt   = (u16*)   (ws + 40 * MB);  //  8 MB  (b,h,d,s') s-permuted
    u16*    Oa   = (u16*)   (ws + 48 * MB);  //  8 MB  attn out (b,s,e) bf16

    prep_kernel<<<8448, 256, 0, stream>>>(x, Wq, Wk, Wv, Wo, pos, xb, wqkv, wob, csn);

    // fused QKV projection + RoPE + relayout
    gemm_qkv<<<dim3(24, 32), 256, 0, stream>>>(xb, wqkv, csn, Qh, Kh, Vt);

    attn_kernel<<<512, 512, 0, stream>>>(Qh, Kh, Vt, Oa);

    gemm_bt<<<dim3(8, 32), 256, 0, stream>>>(Oa, wob, out, 4096, 1024, 1024);
}

// Round 8
// 122.524 us; speedup vs baseline: 4.1537x; 1.0870x over previous
//
#include <hip/hip_runtime.h>
#include <hip/hip_bf16.h>
#include <math.h>

typedef __attribute__((ext_vector_type(4))) float   f32x4;
typedef __attribute__((ext_vector_type(8))) __bf16  bf16x8;
typedef __attribute__((ext_vector_type(8))) unsigned short ushort8;
typedef unsigned short u16;

#define QSCALE 0.1803368801111729f   // 0.125 * log2(e): softmax done in exp2 domain

__device__ __forceinline__ u16 f2b(float f) {
    unsigned u = __builtin_bit_cast(unsigned, f);
    u += 0x7fff + ((u >> 16) & 1);          // RNE
    return (u16)(u >> 16);
}
// async global->LDS, 16B per lane; LDS dest = wave-uniform base + lane*16
__device__ __forceinline__ void gl16(const void* g, void* l) {
    __builtin_amdgcn_global_load_lds((const __attribute__((address_space(1))) void*)g,
                                     (__attribute__((address_space(3))) void*)l, 16, 0, 0);
}
// k-permutation within a 32-elem chunk: dim d stored at pos32(d). Identity:
// pos32(hw_k(j)) = lg*8 + j  ->  MFMA fragment is ONE contiguous 16B read.
__device__ __forceinline__ int pos32(int d) {
    return ((d & 15) >> 2) * 8 + ((d >> 4) & 1) * 4 + (d & 3);
}
// single ds_read_b128 fragment from a 64-col permuted+swizzled LDS tile
__device__ __forceinline__ bf16x8 frag128(const u16* tile, int row, int half, int lg) {
    int gran = (half * 4 + lg) ^ (row & 7);
    return *(const bf16x8*)(tile + row * 64 + gran * 8);
}

// ---------------- fused prep: x/weights f32->bf16 (pos32-k-permuted) + cos/sin table ----------------
// quad q of each 32-chunk moves to quad (q&3)*2 + (q>>2)  ( == pos32 on aligned quads)
__device__ __forceinline__ int permq(int i) {
    int q = i & 7;
    return (i & ~7) | ((q & 3) * 2 + (q >> 2));
}
// blocks [0,4096): x ; [4096,8192): 4 weights ; [8192,8448): csn
__global__ void prep_kernel(const float* __restrict__ x,
                            const float* __restrict__ Wq, const float* __restrict__ Wk,
                            const float* __restrict__ Wv, const float* __restrict__ Wo,
                            const int* __restrict__ pos,
                            u16* __restrict__ xb, u16* __restrict__ wqkv, u16* __restrict__ wob,
                            float2* __restrict__ csn)
{
    int bx = blockIdx.x, tid = threadIdx.x;
    if (bx < 4096) {
        int i = bx * 256 + tid;
        float4 v = ((const float4*)x)[i];
        ((ushort4*)xb)[permq(i)] = make_ushort4(f2b(v.x), f2b(v.y), f2b(v.z), f2b(v.w));
    } else if (bx < 8192) {
        int j = bx - 4096;
        int w = j >> 10;
        int i = (j & 1023) * 256 + tid;
        const float* s = (w == 0) ? Wq : (w == 1) ? Wk : (w == 2) ? Wv : Wo;
        u16* d = (w == 3) ? wob : (wqkv + (size_t)w * 1048576);
        float4 v = ((const float4*)s)[i];
        ((ushort4*)d)[permq(i)] = make_ushort4(f2b(v.x), f2b(v.y), f2b(v.z), f2b(v.w));
    } else {
        int idx = (bx - 8192) * 256 + tid;       // [0, 65536)
        int s = idx >> 5, i = idx & 31;
        float p = (float)pos[s];
        float ang = p * exp2f((float)i * (-13.28771237954945f / 32.f));
        csn[idx] = make_float2(cosf(ang), sinf(ang));
    }
}

// ---- shared GEMM K-loop (BK=64, single-buffer, 2-barrier, frag128): A,B k-permuted ----
// stages A/B 128x64 tiles with inverse-swizzled source granules; computes acc[4][4]
#define GEMM_CORE(A_, B_, Kd_)                                                              \
    for (int kt = 0; kt < (Kd_); kt += 64) {                                                \
        __syncthreads();                                                                    \
        _Pragma("unroll")                                                                   \
        for (int r = 0; r < 4; ++r) {                                                       \
            int c = r * 256 + tid;                                                          \
            int row = c >> 3;                                                               \
            int col = (((c & 7) ^ (row & 7))) * 8;                                          \
            gl16((A_) + (size_t)(mblk + row) * (Kd_) + kt + col, lsA + c * 8);              \
            gl16((B_) + (size_t)(nblk + row) * (Kd_) + kt + col, lsB + c * 8);              \
        }                                                                                   \
        __syncthreads();                                                                    \
        bf16x8 af[4][2], bfr[4][2];                                                         \
        _Pragma("unroll")                                                                   \
        for (int mm = 0; mm < 4; ++mm) {                                                    \
            af[mm][0] = frag128(lsA, m0 + mm * 16 + l15, 0, lg);                            \
            af[mm][1] = frag128(lsA, m0 + mm * 16 + l15, 1, lg);                            \
        }                                                                                   \
        _Pragma("unroll")                                                                   \
        for (int nn = 0; nn < 4; ++nn) {                                                    \
            bfr[nn][0] = frag128(lsB, n0 + nn * 16 + l15, 0, lg);                           \
            bfr[nn][1] = frag128(lsB, n0 + nn * 16 + l15, 1, lg);                           \
        }                                                                                   \
        _Pragma("unroll")                                                                   \
        for (int mm = 0; mm < 4; ++mm)                                                      \
            _Pragma("unroll")                                                               \
            for (int nn = 0; nn < 4; ++nn) {                                                \
                acc[mm][nn] = __builtin_amdgcn_mfma_f32_16x16x32_bf16(af[mm][0], bfr[nn][0], acc[mm][nn], 0, 0, 0); \
                acc[mm][nn] = __builtin_amdgcn_mfma_f32_16x16x32_bf16(af[mm][1], bfr[nn][1], acc[mm][nn], 0, 0, 0); \
            }                                                                               \
    }

// ---------------- fused QKV GEMM: Y = x*Wqkv^T with RoPE/relayout epilogue ----------------
// 768 blocks, XCD-swizzled; role by n-block: 0-7 Qh (rope+scale), 8-15 Kh, 16-23 Vt
__global__ __launch_bounds__(256) void gemm_qkv(
    const u16* __restrict__ A, const u16* __restrict__ Bw, const float2* __restrict__ csn,
    u16* __restrict__ Qh, u16* __restrict__ Kh, u16* __restrict__ Vt)
{
    __shared__ u16 shm[128 * 132];               // K-loop: A[0,8192) B[8192,16384); V-epi: 128x132
    u16* lsA = shm;
    u16* lsB = shm + 8192;
    const int tid = threadIdx.x;
    const int lane = tid & 63, wv = tid >> 6;
    const int l15 = lane & 15, lg = lane >> 4;
    // bijective XCD swizzle: each XCD gets 96 consecutive slots = 4 full M-rows of 24
    const int id = blockIdx.x;
    const int nid = (id & 7) * 96 + (id >> 3);
    const int bx = nid % 24, by = nid / 24;
    const int mblk = by * 128, nblk = bx * 128;
    const int m0 = (wv >> 1) * 64, n0 = (wv & 1) * 64;

    f32x4 acc[4][4];
    for (int a = 0; a < 4; ++a)
        for (int b = 0; b < 4; ++b)
            for (int r = 0; r < 4; ++r) acc[a][b][r] = 0.f;

    GEMM_CORE(A, Bw, 1024)

    const int role = nblk >> 10;                 // 0=Q, 1=K, 2=V
    if (role < 2) {
        // RoPE epilogue: partner value lives in lane^1 (adjacent e)
        u16* dst = role ? Kh : Qh;
        const float scale = role ? 1.f : QSCALE;
#pragma unroll
        for (int mm = 0; mm < 4; ++mm)
#pragma unroll
            for (int nn = 0; nn < 4; ++nn) {
                int colq = (nblk + n0 + nn * 16 + l15) & 1023;
                int h = colq >> 6, dd = colq & 63;
                int outd = (dd & 32) + pos32(dd & 31);
                int odd = dd & 1, i = dd >> 1;
#pragma unroll
                for (int r = 0; r < 4; ++r) {
                    int rowg = mblk + m0 + mm * 16 + lg * 4 + r;
                    int b = rowg >> 11, s = rowg & 2047;
                    float2 cs = csn[s * 32 + i];
                    float v = acc[mm][nn][r];
                    float p = __shfl_xor(v, 1);
                    float o = odd ? (p * cs.y + v * cs.x) : (v * cs.x - p * cs.y);
                    dst[((size_t)(b * 16 + h) * 2048 + s) * 64 + outd] = f2b(o * scale);
                }
            }
    } else {
        // V transpose epilogue via LDS
        __syncthreads();                         // all waves done reading gemm bufs
#pragma unroll
        for (int mm = 0; mm < 4; ++mm)
#pragma unroll
            for (int nn = 0; nn < 4; ++nn)
#pragma unroll
                for (int r = 0; r < 4; ++r)
                    shm[(m0 + mm * 16 + lg * 4 + r) * 132 + n0 + nn * 16 + l15] = f2b(acc[mm][nn][r]);
        __syncthreads();
        const int el = tid >> 1, half = tid & 1;
        const int colg = nblk - 2048 + el;
        const int h = colg >> 6, dd = colg & 63;
        const int b = mblk >> 11;
        const int sbase = (mblk & 2047) + half * 64;
        u16 vals[64];
#pragma unroll
        for (int o = 0; o < 64; ++o) {
            int oo = o & 31;
            int d = (o & 32) + ((oo >> 2) & 1) * 16 + (oo >> 3) * 4 + (oo & 3);
            vals[o] = shm[(half * 64 + d) * 132 + el];
        }
        u16* dst = Vt + ((size_t)(b * 16 + h) * 64 + dd) * 2048 + sbase;
#pragma unroll
        for (int a = 0; a < 8; ++a)
            *(ushort8*)(dst + a * 8) = *(const ushort8*)(vals + a * 8);
    }
}

// ---------------- out-proj GEMM: C[4096,1024] = Oa * Wo^T -> f32 ----------------
// 256 blocks, XCD-swizzled (32 slots = 4 M-rows of 8)
__global__ __launch_bounds__(256) void gemm_bt(
    const u16* __restrict__ A, const u16* __restrict__ Bw, float* __restrict__ Cf)
{
    __shared__ u16 shm[16384];
    u16* lsA = shm;
    u16* lsB = shm + 8192;
    const int tid = threadIdx.x;
    const int lane = tid & 63, wv = tid >> 6;
    const int l15 = lane & 15, lg = lane >> 4;
    const int id = blockIdx.x;
    const int nid = (id & 7) * 32 + (id >> 3);
    const int bx = nid & 7, by = nid >> 3;
    const int mblk = by * 128, nblk = bx * 128;
    const int m0 = (wv >> 1) * 64, n0 = (wv & 1) * 64;

    f32x4 acc[4][4];
    for (int a = 0; a < 4; ++a)
        for (int b = 0; b < 4; ++b)
            for (int r = 0; r < 4; ++r) acc[a][b][r] = 0.f;

    GEMM_CORE(A, Bw, 1024)

#pragma unroll
    for (int mm = 0; mm < 4; ++mm)
#pragma unroll
        for (int nn = 0; nn < 4; ++nn)
#pragma unroll
            for (int r = 0; r < 4; ++r) {
                int row = mblk + m0 + mm * 16 + lg * 4 + r;
                int col = nblk + n0 + nn * 16 + l15;
                Cf[(size_t)row * 1024 + col] = acc[mm][nn][r];
            }
}

// ---------------- Flash attention: 8 waves, QBLK=128, KVBLK=128, dbuf, causal-split ----------------
__device__ __forceinline__ void stage_kv128(const u16* Kp, const u16* Vp, int t,
                                            u16* bK, u16* bV, int tid, int wv) {
#pragma unroll
    for (int r = 0; r < 2; ++r) {
        int c = r * 512 + tid;
        int krow = c >> 3;                       // key-local 0..127
        int kcol = ((c & 7) ^ (krow & 7)) * 8;
        gl16(Kp + (size_t)(t * 128 + krow) * 64 + kcol, bK + (r * 512 + wv * 64) * 8);
        int d = krow & 63, ss = krow >> 6;       // V: rows d, subtile ss
        int vcol = ((c & 7) ^ (d & 7)) * 8;
        gl16(Vp + (size_t)d * 2048 + t * 128 + ss * 64 + vcol, bV + (r * 512 + wv * 64) * 8);
    }
}
__global__ __launch_bounds__(512) void attn_kernel(
    const u16* __restrict__ Qh, const u16* __restrict__ Kh, const u16* __restrict__ Vt,
    u16* __restrict__ Oa)
{
    __shared__ u16 shm[32768];                   // 64 KB
    const int tid = threadIdx.x;
    const int lane = tid & 63, wv = tid >> 6;    // wv 0..7
    const int l15 = lane & 15, lg = lane >> 4;
    const int id = blockIdx.x;
    const int gq = id >> 5;
    const int qt = (id < 256) ? (15 - gq) : (gq - 8);   // heavy+light pairing
    const int bh = id & 31;
    const int b = bh >> 4, h = bh & 15;
    const u16* Qp = Qh + (size_t)bh * 2048 * 64;
    const u16* Kp = Kh + (size_t)bh * 2048 * 64;
    const u16* Vp = Vt + (size_t)bh * 64 * 2048;

    // stage Q (128x64) into shm[0,8192)
#pragma unroll
    for (int r = 0; r < 2; ++r) {
        int c = r * 512 + tid;
        int row = c >> 3;
        int col = ((c & 7) ^ (row & 7)) * 8;
        gl16(Qp + (size_t)(qt * 128 + row) * 64 + col, shm + (r * 512 + wv * 64) * 8);
    }
    __syncthreads();
    bf16x8 qf[2];                                // wave's 16 q-rows
#pragma unroll
    for (int ds = 0; ds < 2; ++ds)
        qf[ds] = frag128(shm, wv * 16 + l15, ds, lg);
    __syncthreads();                             // everyone done reading Q

    stage_kv128(Kp, Vp, 0, shm, shm + 16384, tid, wv);
    __syncthreads();                             // KV tile 0 ready

    f32x4 accO[4];
#pragma unroll
    for (int dm = 0; dm < 4; ++dm)
        for (int r = 0; r < 4; ++r) accO[dm][r] = 0.f;
    float mrun = -3e38f, lrun = 0.f;
    const int st_b = 2 * qt + (wv >> 2);         // boundary 64-key subtile for this wave
    const int NT = qt + 1;                       // 128-key tiles

    for (int t = 0; t < NT; ++t) {
        const int cur = t & 1;
        if (t + 1 < NT)
            stage_kv128(Kp, Vp, t + 1, shm + (cur ^ 1) * 8192, shm + 16384 + (cur ^ 1) * 8192, tid, wv);
        const u16* Kt = shm + cur * 8192;
        const u16* Vb = shm + 16384 + cur * 8192;
#pragma unroll
        for (int ss = 0; ss < 2; ++ss) {
            const int st = 2 * t + ss;
            if (st <= st_b) {
                f32x4 sa[4];
                __builtin_amdgcn_s_setprio(1);
#pragma unroll
                for (int kb = 0; kb < 4; ++kb) {
                    int krow = ss * 64 + kb * 16 + l15;
                    bf16x8 kf0 = frag128(Kt, krow, 0, lg);
                    bf16x8 kf1 = frag128(Kt, krow, 1, lg);
                    f32x4 s = { 0.f, 0.f, 0.f, 0.f };
                    s = __builtin_amdgcn_mfma_f32_16x16x32_bf16(kf0, qf[0], s, 0, 0, 0);
                    s = __builtin_amdgcn_mfma_f32_16x16x32_bf16(kf1, qf[1], s, 0, 0, 0);
                    sa[kb] = s;
                }
                __builtin_amdgcn_s_setprio(0);
                if (st == st_b) {                // boundary subtile: causal mask
                    int qg = qt * 128 + wv * 16 + l15;
#pragma unroll
                    for (int kb = 0; kb < 4; ++kb)
#pragma unroll
                        for (int r = 0; r < 4; ++r)
                            if (st * 64 + kb * 16 + lg * 4 + r > qg) sa[kb][r] = -1e30f;
                }
                float a0 = fmaxf(fmaxf(sa[0][0], sa[0][1]), fmaxf(sa[0][2], sa[0][3]));
                float a1 = fmaxf(fmaxf(sa[1][0], sa[1][1]), fmaxf(sa[1][2], sa[1][3]));
                float a2 = fmaxf(fmaxf(sa[2][0], sa[2][1]), fmaxf(sa[2][2], sa[2][3]));
                float a3 = fmaxf(fmaxf(sa[3][0], sa[3][1]), fmaxf(sa[3][2], sa[3][3]));
                float pm = fmaxf(fmaxf(a0, a1), fmaxf(a2, a3));
                pm = fmaxf(pm, __shfl_xor(pm, 16));
                pm = fmaxf(pm, __shfl_xor(pm, 32));
                // T13 defer-max
                if (!__all(pm <= mrun + 8.f)) {
                    float mnew = fmaxf(mrun, pm);
                    float fac = exp2f(mrun - mnew);
                    lrun *= fac;
#pragma unroll
                    for (int dm = 0; dm < 4; ++dm)
#pragma unroll
                        for (int r = 0; r < 4; ++r) accO[dm][r] *= fac;
                    mrun = mnew;
                }
                float ps = 0.f;
#pragma unroll
                for (int kb = 0; kb < 4; ++kb)
#pragma unroll
                    for (int r = 0; r < 4; ++r) {
                        float pe = exp2f(sa[kb][r] - mrun);
                        sa[kb][r] = pe;
                        ps += pe;
                    }
                ps += __shfl_xor(ps, 16);
                ps += __shfl_xor(ps, 32);
                lrun += ps;
                bf16x8 pf[2];
#pragma unroll
                for (int ks = 0; ks < 2; ++ks) {
                    bf16x8 tt;
#pragma unroll
                    for (int j = 0; j < 4; ++j) {
                        tt[j]     = (__bf16)sa[2 * ks][j];
                        tt[4 + j] = (__bf16)sa[2 * ks + 1][j];
                    }
                    pf[ks] = tt;
                }
                __builtin_amdgcn_s_setprio(1);
#pragma unroll
                for (int dm = 0; dm < 4; ++dm) {
                    int vrow = ss * 64 + dm * 16 + l15;
#pragma unroll
                    for (int ks = 0; ks < 2; ++ks) {
                        bf16x8 vf = frag128(Vb, vrow, ks, lg);
                        accO[dm] = __builtin_amdgcn_mfma_f32_16x16x32_bf16(vf, pf[ks], accO[dm], 0, 0, 0);
                    }
                }
                __builtin_amdgcn_s_setprio(0);
            }
        }
        __syncthreads();                         // next tile staged + this tile's reads done
    }
    float inv = 1.f / lrun;
    int srow = qt * 128 + wv * 16 + l15;
#pragma unroll
    for (int dm = 0; dm < 4; ++dm) {
        // Oa written pos32-k-permuted (it feeds gemm_bt's A): quad remap within 32-chunk
        int cb = h * 64 + dm * 16 + lg * 4;
        int q = (cb >> 2) & 7;
        int cbp = (cb & ~31) | (((q & 3) * 2 + (q >> 2)) * 4);
        ushort4 o = make_ushort4(f2b(accO[dm][0] * inv), f2b(accO[dm][1] * inv),
                                 f2b(accO[dm][2] * inv), f2b(accO[dm][3] * inv));
        *(ushort4*)&Oa[((size_t)b * 2048 + srow) * 1024 + cbp] = o;
    }
}

extern "C" void kernel_launch(void* const* d_in, const int* in_sizes, int n_in,
                              void* d_out, int out_size, void* d_ws, size_t ws_size,
                              hipStream_t stream) {
    const float* x  = (const float*)d_in[0];
    const int*   pos = (const int*)d_in[1];
    const float* Wq = (const float*)d_in[2];
    const float* Wk = (const float*)d_in[3];
    const float* Wv = (const float*)d_in[4];
    const float* Wo = (const float*)d_in[5];
    float* out = (float*)d_out;
    char* ws = (char*)d_ws;
    const size_t MB = 1024 * 1024;
    u16*    xb   = (u16*)   (ws + 0);        //  8 MB  x bf16, k-permuted
    u16*    wqkv = (u16*)   (ws + 8  * MB);  //  6 MB  [Wq;Wk;Wv], k-permuted
    u16*    wob  = (u16*)   (ws + 14 * MB);  //  2 MB  k-permuted
    float2* csn  = (float2*)(ws + 16 * MB);  //  0.5 MB cos/sin table (2048x32)
    u16*    Qh   = (u16*)   (ws + 24 * MB);  //  8 MB  (b,h,s,d') pre-scaled, d-permuted
    u16*    Kh   = (u16*)   (ws + 32 * MB);  //  8 MB  (b,h,s,d') d-permuted
    u16*    Vt   = (u16*)   (ws + 40 * MB);  //  8 MB  (b,h,d,s') s-permuted
    u16*    Oa   = (u16*)   (ws + 48 * MB);  //  8 MB  attn out (b,s,e') k-permuted

    prep_kernel<<<8448, 256, 0, stream>>>(x, Wq, Wk, Wv, Wo, pos, xb, wqkv, wob, csn);

    gemm_qkv<<<768, 256, 0, stream>>>(xb, wqkv, csn, Qh, Kh, Vt);

    attn_kernel<<<512, 512, 0, stream>>>(Qh, Kh, Vt, Oa);

    gemm_bt<<<256, 256, 0, stream>>>(Oa, wob, out);
}

// Round 9
// 109.638 us; speedup vs baseline: 4.6419x; 1.1175x over previous
//
#include <hip/hip_runtime.h>
#include <hip/hip_bf16.h>
#include <math.h>

typedef __attribute__((ext_vector_type(4))) float   f32x4;
typedef __attribute__((ext_vector_type(8))) __bf16  bf16x8;
typedef __attribute__((ext_vector_type(8))) unsigned short ushort8;
typedef unsigned short u16;

#define QSCALE 0.1803368801111729f   // 0.125 * log2(e): softmax done in exp2 domain

__device__ __forceinline__ u16 f2b(float f) {
    unsigned u = __builtin_bit_cast(unsigned, f);
    u += 0x7fff + ((u >> 16) & 1);          // RNE
    return (u16)(u >> 16);
}
// async global->LDS, 16B per lane; LDS dest = wave-uniform base + lane*16
__device__ __forceinline__ void gl16(const void* g, void* l) {
    __builtin_amdgcn_global_load_lds((const __attribute__((address_space(1))) void*)g,
                                     (__attribute__((address_space(3))) void*)l, 16, 0, 0);
}
// k-permutation within a 32-elem chunk: dim d stored at pos32(d). Identity:
// pos32(hw_k(j)) = lg*8 + j  ->  MFMA fragment is ONE contiguous 16B read.
__device__ __forceinline__ int pos32(int d) {
    return ((d & 15) >> 2) * 8 + ((d >> 4) & 1) * 4 + (d & 3);
}
// single ds_read_b128 fragment from a 64-col permuted+swizzled LDS tile
__device__ __forceinline__ bf16x8 frag128(const u16* tile, int row, int half, int lg) {
    int gran = (half * 4 + lg) ^ (row & 7);
    return *(const bf16x8*)(tile + row * 64 + gran * 8);
}

// ---------------- fused prep: x/weights f32->bf16 (pos32-k-permuted) + cos/sin table ----------------
// quad q of each 32-chunk moves to quad (q&3)*2 + (q>>2)  ( == pos32 on aligned quads)
__device__ __forceinline__ int permq(int i) {
    int q = i & 7;
    return (i & ~7) | ((q & 3) * 2 + (q >> 2));
}
// blocks [0,4096): x ; [4096,8192): 4 weights ; [8192,8448): csn
__global__ void prep_kernel(const float* __restrict__ x,
                            const float* __restrict__ Wq, const float* __restrict__ Wk,
                            const float* __restrict__ Wv, const float* __restrict__ Wo,
                            const int* __restrict__ pos,
                            u16* __restrict__ xb, u16* __restrict__ wqkv, u16* __restrict__ wob,
                            float2* __restrict__ csn)
{
    int bx = blockIdx.x, tid = threadIdx.x;
    if (bx < 4096) {
        int i = bx * 256 + tid;
        float4 v = ((const float4*)x)[i];
        ((ushort4*)xb)[permq(i)] = make_ushort4(f2b(v.x), f2b(v.y), f2b(v.z), f2b(v.w));
    } else if (bx < 8192) {
        int j = bx - 4096;
        int w = j >> 10;
        int i = (j & 1023) * 256 + tid;
        const float* s = (w == 0) ? Wq : (w == 1) ? Wk : (w == 2) ? Wv : Wo;
        u16* d = (w == 3) ? wob : (wqkv + (size_t)w * 1048576);
        float4 v = ((const float4*)s)[i];
        ((ushort4*)d)[permq(i)] = make_ushort4(f2b(v.x), f2b(v.y), f2b(v.z), f2b(v.w));
    } else {
        int idx = (bx - 8192) * 256 + tid;       // [0, 65536)
        int s = idx >> 5, i = idx & 31;
        float p = (float)pos[s];
        float ang = p * exp2f((float)i * (-13.28771237954945f / 32.f));
        csn[idx] = make_float2(cosf(ang), sinf(ang));
    }
}

// ---- GEMM K-loop: BK=64, LDS double-buffered, stage-next-then-compute (m97 schedule) ----
// lsA/lsB are 2x8192 u16 regions; A,B are pos32-k-permuted in global.
#define GEMM_STAGE(A_, B_, Kd_, kt_, dA_, dB_)                                              \
    _Pragma("unroll")                                                                       \
    for (int r = 0; r < 4; ++r) {                                                           \
        int c = r * 256 + tid;                                                              \
        int row = c >> 3;                                                                   \
        int col = (((c & 7) ^ (row & 7))) * 8;                                              \
        gl16((A_) + (size_t)(mblk + row) * (Kd_) + (kt_) + col, (dA_) + c * 8);             \
        gl16((B_) + (size_t)(nblk + row) * (Kd_) + (kt_) + col, (dB_) + c * 8);             \
    }

#define GEMM_CORE(A_, B_, Kd_)                                                              \
    GEMM_STAGE(A_, B_, Kd_, 0, lsA, lsB)                                                    \
    for (int it = 0; it < (Kd_) >> 6; ++it) {                                               \
        const int cur = it & 1;                                                             \
        const u16* cA = lsA + cur * 8192;                                                   \
        const u16* cB = lsB + cur * 8192;                                                   \
        __syncthreads();    /* buf[cur] staged; prev reads of buf[cur^1] done */            \
        if (it + 1 < ((Kd_) >> 6)) {                                                        \
            GEMM_STAGE(A_, B_, Kd_, (it + 1) * 64, lsA + (cur ^ 1) * 8192,                  \
                       lsB + (cur ^ 1) * 8192)                                              \
        }                                                                                   \
        bf16x8 af[4][2], bfr[4][2];                                                         \
        _Pragma("unroll")                                                                   \
        for (int mm = 0; mm < 4; ++mm) {                                                    \
            af[mm][0] = frag128(cA, m0 + mm * 16 + l15, 0, lg);                             \
            af[mm][1] = frag128(cA, m0 + mm * 16 + l15, 1, lg);                             \
        }                                                                                   \
        _Pragma("unroll")                                                                   \
        for (int nn = 0; nn < 4; ++nn) {                                                    \
            bfr[nn][0] = frag128(cB, n0 + nn * 16 + l15, 0, lg);                            \
            bfr[nn][1] = frag128(cB, n0 + nn * 16 + l15, 1, lg);                            \
        }                                                                                   \
        _Pragma("unroll")                                                                   \
        for (int mm = 0; mm < 4; ++mm)                                                      \
            _Pragma("unroll")                                                               \
            for (int nn = 0; nn < 4; ++nn) {                                                \
                acc[mm][nn] = __builtin_amdgcn_mfma_f32_16x16x32_bf16(af[mm][0], bfr[nn][0], acc[mm][nn], 0, 0, 0); \
                acc[mm][nn] = __builtin_amdgcn_mfma_f32_16x16x32_bf16(af[mm][1], bfr[nn][1], acc[mm][nn], 0, 0, 0); \
            }                                                                               \
    }

// ---------------- fused QKV GEMM: Y = x*Wqkv^T with RoPE/relayout epilogue ----------------
// 768 blocks; squarish per-XCD tile (12 N-cols x 8 M-rows) for A+B L2 locality
__global__ __launch_bounds__(256) void gemm_qkv(
    const u16* __restrict__ A, const u16* __restrict__ Bw, const float2* __restrict__ csn,
    u16* __restrict__ Qh, u16* __restrict__ Kh, u16* __restrict__ Vt)
{
    __shared__ u16 shm[32768];                   // 64 KB: A dbuf [0,16384), B dbuf [16384,32768)
    u16* lsA = shm;
    u16* lsB = shm + 16384;
    const int tid = threadIdx.x;
    const int lane = tid & 63, wv = tid >> 6;
    const int l15 = lane & 15, lg = lane >> 4;
    const int id = blockIdx.x;
    const int xcd = id & 7, slot = id >> 3;      // 96 slots/XCD
    const int bx = (xcd & 1) * 12 + slot % 12;   // 2 XCDs across N, 4 down M
    const int by = (xcd >> 1) * 8 + slot / 12;
    const int mblk = by * 128, nblk = bx * 128;
    const int m0 = (wv >> 1) * 64, n0 = (wv & 1) * 64;

    f32x4 acc[4][4];
    for (int a = 0; a < 4; ++a)
        for (int b = 0; b < 4; ++b)
            for (int r = 0; r < 4; ++r) acc[a][b][r] = 0.f;

    GEMM_CORE(A, Bw, 1024)

    const int role = nblk >> 10;                 // 0=Q, 1=K, 2=V
    if (role < 2) {
        // RoPE epilogue: partner value lives in lane^1 (adjacent e)
        u16* dst = role ? Kh : Qh;
        const float scale = role ? 1.f : QSCALE;
#pragma unroll
        for (int mm = 0; mm < 4; ++mm)
#pragma unroll
            for (int nn = 0; nn < 4; ++nn) {
                int colq = (nblk + n0 + nn * 16 + l15) & 1023;
                int h = colq >> 6, dd = colq & 63;
                int outd = (dd & 32) + pos32(dd & 31);
                int odd = dd & 1, i = dd >> 1;
#pragma unroll
                for (int r = 0; r < 4; ++r) {
                    int rowg = mblk + m0 + mm * 16 + lg * 4 + r;
                    int b = rowg >> 11, s = rowg & 2047;
                    float2 cs = csn[s * 32 + i];
                    float v = acc[mm][nn][r];
                    float p = __shfl_xor(v, 1);
                    float o = odd ? (p * cs.y + v * cs.x) : (v * cs.x - p * cs.y);
                    dst[((size_t)(b * 16 + h) * 2048 + s) * 64 + outd] = f2b(o * scale);
                }
            }
    } else {
        // V transpose epilogue via LDS (reuses shm; fits in 64 KB)
        __syncthreads();                         // all waves done reading gemm bufs
#pragma unroll
        for (int mm = 0; mm < 4; ++mm)
#pragma unroll
            for (int nn = 0; nn < 4; ++nn)
#pragma unroll
                for (int r = 0; r < 4; ++r)
                    shm[(m0 + mm * 16 + lg * 4 + r) * 132 + n0 + nn * 16 + l15] = f2b(acc[mm][nn][r]);
        __syncthreads();
        const int el = tid >> 1, half = tid & 1;
        const int colg = nblk - 2048 + el;
        const int h = colg >> 6, dd = colg & 63;
        const int b = mblk >> 11;
        const int sbase = (mblk & 2047) + half * 64;
        u16 vals[64];
#pragma unroll
        for (int o = 0; o < 64; ++o) {
            int oo = o & 31;
            int d = (o & 32) + ((oo >> 2) & 1) * 16 + (oo >> 3) * 4 + (oo & 3);
            vals[o] = shm[(half * 64 + d) * 132 + el];
        }
        u16* dst = Vt + ((size_t)(b * 16 + h) * 64 + dd) * 2048 + sbase;
#pragma unroll
        for (int a = 0; a < 8; ++a)
            *(ushort8*)(dst + a * 8) = *(const ushort8*)(vals + a * 8);
    }
}

// ---------------- out-proj GEMM: C[4096,1024] = Oa * Wo^T -> f32 ----------------
// 256 blocks; per-XCD tile 4 N x 8 M
__global__ __launch_bounds__(256) void gemm_bt(
    const u16* __restrict__ A, const u16* __restrict__ Bw, float* __restrict__ Cf)
{
    __shared__ u16 shm[32768];
    u16* lsA = shm;
    u16* lsB = shm + 16384;
    const int tid = threadIdx.x;
    const int lane = tid & 63, wv = tid >> 6;
    const int l15 = lane & 15, lg = lane >> 4;
    const int id = blockIdx.x;
    const int xcd = id & 7, slot = id >> 3;      // 32 slots/XCD
    const int bx = (xcd & 1) * 4 + (slot & 3);
    const int by = (xcd >> 1) * 8 + (slot >> 2);
    const int mblk = by * 128, nblk = bx * 128;
    const int m0 = (wv >> 1) * 64, n0 = (wv & 1) * 64;

    f32x4 acc[4][4];
    for (int a = 0; a < 4; ++a)
        for (int b = 0; b < 4; ++b)
            for (int r = 0; r < 4; ++r) acc[a][b][r] = 0.f;

    GEMM_CORE(A, Bw, 1024)

#pragma unroll
    for (int mm = 0; mm < 4; ++mm)
#pragma unroll
        for (int nn = 0; nn < 4; ++nn)
#pragma unroll
            for (int r = 0; r < 4; ++r) {
                int row = mblk + m0 + mm * 16 + lg * 4 + r;
                int col = nblk + n0 + nn * 16 + l15;
                Cf[(size_t)row * 1024 + col] = acc[mm][nn][r];
            }
}

// ---------------- Flash attention: 8 waves, QBLK=128, KVBLK=128, dbuf, causal-split ----------------
__device__ __forceinline__ void stage_kv128(const u16* Kp, const u16* Vp, int t,
                                            u16* bK, u16* bV, int tid, int wv) {
#pragma unroll
    for (int r = 0; r < 2; ++r) {
        int c = r * 512 + tid;
        int krow = c >> 3;                       // key-local 0..127
        int kcol = ((c & 7) ^ (krow & 7)) * 8;
        gl16(Kp + (size_t)(t * 128 + krow) * 64 + kcol, bK + (r * 512 + wv * 64) * 8);
        int d = krow & 63, ss = krow >> 6;       // V: rows d, subtile ss
        int vcol = ((c & 7) ^ (d & 7)) * 8;
        gl16(Vp + (size_t)d * 2048 + t * 128 + ss * 64 + vcol, bV + (r * 512 + wv * 64) * 8);
    }
}
__global__ __launch_bounds__(512) void attn_kernel(
    const u16* __restrict__ Qh, const u16* __restrict__ Kh, const u16* __restrict__ Vt,
    u16* __restrict__ Oa)
{
    __shared__ u16 shm[32768];                   // 64 KB
    const int tid = threadIdx.x;
    const int lane = tid & 63, wv = tid >> 6;    // wv 0..7
    const int l15 = lane & 15, lg = lane >> 4;
    const int id = blockIdx.x;
    const int gq = id >> 5;
    const int qt = (id < 256) ? (15 - gq) : (gq - 8);   // heavy+light pairing
    const int bh = id & 31;
    const int b = bh >> 4, h = bh & 15;
    const u16* Qp = Qh + (size_t)bh * 2048 * 64;
    const u16* Kp = Kh + (size_t)bh * 2048 * 64;
    const u16* Vp = Vt + (size_t)bh * 64 * 2048;

    // stage Q (128x64) into shm[0,8192)
#pragma unroll
    for (int r = 0; r < 2; ++r) {
        int c = r * 512 + tid;
        int row = c >> 3;
        int col = ((c & 7) ^ (row & 7)) * 8;
        gl16(Qp + (size_t)(qt * 128 + row) * 64 + col, shm + (r * 512 + wv * 64) * 8);
    }
    __syncthreads();
    bf16x8 qf[2];                                // wave's 16 q-rows
#pragma unroll
    for (int ds = 0; ds < 2; ++ds)
        qf[ds] = frag128(shm, wv * 16 + l15, ds, lg);
    __syncthreads();                             // everyone done reading Q

    stage_kv128(Kp, Vp, 0, shm, shm + 16384, tid, wv);
    __syncthreads();                             // KV tile 0 ready

    f32x4 accO[4];
#pragma unroll
    for (int dm = 0; dm < 4; ++dm)
        for (int r = 0; r < 4; ++r) accO[dm][r] = 0.f;
    float mrun = -3e38f, lrun = 0.f;
    const int st_b = 2 * qt + (wv >> 2);         // boundary 64-key subtile for this wave
    const int NT = qt + 1;                       // 128-key tiles

    for (int t = 0; t < NT; ++t) {
        const int cur = t & 1;
        if (t + 1 < NT)
            stage_kv128(Kp, Vp, t + 1, shm + (cur ^ 1) * 8192, shm + 16384 + (cur ^ 1) * 8192, tid, wv);
        const u16* Kt = shm + cur * 8192;
        const u16* Vb = shm + 16384 + cur * 8192;
#pragma unroll
        for (int ss = 0; ss < 2; ++ss) {
            const int st = 2 * t + ss;
            if (st <= st_b) {
                f32x4 sa[4];
                __builtin_amdgcn_s_setprio(1);
#pragma unroll
                for (int kb = 0; kb < 4; ++kb) {
                    int krow = ss * 64 + kb * 16 + l15;
                    bf16x8 kf0 = frag128(Kt, krow, 0, lg);
                    bf16x8 kf1 = frag128(Kt, krow, 1, lg);
                    f32x4 s = { 0.f, 0.f, 0.f, 0.f };
                    s = __builtin_amdgcn_mfma_f32_16x16x32_bf16(kf0, qf[0], s, 0, 0, 0);
                    s = __builtin_amdgcn_mfma_f32_16x16x32_bf16(kf1, qf[1], s, 0, 0, 0);
                    sa[kb] = s;
                }
                __builtin_amdgcn_s_setprio(0);
                if (st == st_b) {                // boundary subtile: causal mask
                    int qg = qt * 128 + wv * 16 + l15;
#pragma unroll
                    for (int kb = 0; kb < 4; ++kb)
#pragma unroll
                        for (int r = 0; r < 4; ++r)
                            if (st * 64 + kb * 16 + lg * 4 + r > qg) sa[kb][r] = -1e30f;
                }
                float a0 = fmaxf(fmaxf(sa[0][0], sa[0][1]), fmaxf(sa[0][2], sa[0][3]));
                float a1 = fmaxf(fmaxf(sa[1][0], sa[1][1]), fmaxf(sa[1][2], sa[1][3]));
                float a2 = fmaxf(fmaxf(sa[2][0], sa[2][1]), fmaxf(sa[2][2], sa[2][3]));
                float a3 = fmaxf(fmaxf(sa[3][0], sa[3][1]), fmaxf(sa[3][2], sa[3][3]));
                float pm = fmaxf(fmaxf(a0, a1), fmaxf(a2, a3));
                pm = fmaxf(pm, __shfl_xor(pm, 16));
                pm = fmaxf(pm, __shfl_xor(pm, 32));
                // T13 defer-max
                if (!__all(pm <= mrun + 8.f)) {
                    float mnew = fmaxf(mrun, pm);
                    float fac = exp2f(mrun - mnew);
                    lrun *= fac;
#pragma unroll
                    for (int dm = 0; dm < 4; ++dm)
#pragma unroll
                        for (int r = 0; r < 4; ++r) accO[dm][r] *= fac;
                    mrun = mnew;
                }
                float ps = 0.f;
#pragma unroll
                for (int kb = 0; kb < 4; ++kb)
#pragma unroll
                    for (int r = 0; r < 4; ++r) {
                        float pe = exp2f(sa[kb][r] - mrun);
                        sa[kb][r] = pe;
                        ps += pe;
                    }
                ps += __shfl_xor(ps, 16);
                ps += __shfl_xor(ps, 32);
                lrun += ps;
                bf16x8 pf[2];
#pragma unroll
                for (int ks = 0; ks < 2; ++ks) {
                    bf16x8 tt;
#pragma unroll
                    for (int j = 0; j < 4; ++j) {
                        tt[j]     = (__bf16)sa[2 * ks][j];
                        tt[4 + j] = (__bf16)sa[2 * ks + 1][j];
                    }
                    pf[ks] = tt;
                }
                __builtin_amdgcn_s_setprio(1);
#pragma unroll
                for (int dm = 0; dm < 4; ++dm) {
                    int vrow = ss * 64 + dm * 16 + l15;
#pragma unroll
                    for (int ks = 0; ks < 2; ++ks) {
                        bf16x8 vf = frag128(Vb, vrow, ks, lg);
                        accO[dm] = __builtin_amdgcn_mfma_f32_16x16x32_bf16(vf, pf[ks], accO[dm], 0, 0, 0);
                    }
                }
                __builtin_amdgcn_s_setprio(0);
            }
        }
        __syncthreads();                         // next tile staged + this tile's reads done
    }
    float inv = 1.f / lrun;
    int srow = qt * 128 + wv * 16 + l15;
#pragma unroll
    for (int dm = 0; dm < 4; ++dm) {
        // Oa written pos32-k-permuted (it feeds gemm_bt's A): quad remap within 32-chunk
        int cb = h * 64 + dm * 16 + lg * 4;
        int q = (cb >> 2) & 7;
        int cbp = (cb & ~31) | (((q & 3) * 2 + (q >> 2)) * 4);
        ushort4 o = make_ushort4(f2b(accO[dm][0] * inv), f2b(accO[dm][1] * inv),
                                 f2b(accO[dm][2] * inv), f2b(accO[dm][3] * inv));
        *(ushort4*)&Oa[((size_t)b * 2048 + srow) * 1024 + cbp] = o;
    }
}

extern "C" void kernel_launch(void* const* d_in, const int* in_sizes, int n_in,
                              void* d_out, int out_size, void* d_ws, size_t ws_size,
                              hipStream_t stream) {
    const float* x  = (const float*)d_in[0];
    const int*   pos = (const int*)d_in[1];
    const float* Wq = (const float*)d_in[2];
    const float* Wk = (const float*)d_in[3];
    const float* Wv = (const float*)d_in[4];
    const float* Wo = (const float*)d_in[5];
    float* out = (float*)d_out;
    char* ws = (char*)d_ws;
    const size_t MB = 1024 * 1024;
    u16*    xb   = (u16*)   (ws + 0);        //  8 MB  x bf16, k-permuted
    u16*    wqkv = (u16*)   (ws + 8  * MB);  //  6 MB  [Wq;Wk;Wv], k-permuted
    u16*    wob  = (u16*)   (ws + 14 * MB);  //  2 MB  k-permuted
    float2* csn  = (float2*)(ws + 16 * MB);  //  0.5 MB cos/sin table (2048x32)
    u16*    Qh   = (u16*)   (ws + 24 * MB);  //  8 MB  (b,h,s,d') pre-scaled, d-permuted
    u16*    Kh   = (u16*)   (ws + 32 * MB);  //  8 MB  (b,h,s,d') d-permuted
    u16*    Vt   = (u16*)   (ws + 40 * MB);  //  8 MB  (b,h,d,s') s-permuted
    u16*    Oa   = (u16*)   (ws + 48 * MB);  //  8 MB  attn out (b,s,e') k-permuted

    prep_kernel<<<8448, 256, 0, stream>>>(x, Wq, Wk, Wv, Wo, pos, xb, wqkv, wob, csn);

    gemm_qkv<<<768, 256, 0, stream>>>(xb, wqkv, csn, Qh, Kh, Vt);

    attn_kernel<<<512, 512, 0, stream>>>(Qh, Kh, Vt, Oa);

    gemm_bt<<<256, 256, 0, stream>>>(Oa, wob, out);
}